// Round 9
// baseline (1136.236 us; speedup 1.0000x reference)
//
#include <hip/hip_runtime.h>
#include <hip/hip_bf16.h>
#include <math.h>

#define BATCH 256
#define NEDGE 4096
#define HDIM 256

typedef __attribute__((ext_vector_type(8))) short short8v;   // 8 bf16 = 4 VGPR
typedef __attribute__((ext_vector_type(4))) float float4v;

__device__ __forceinline__ float gelu_f(float x) {
  // jax.nn.gelu approximate=True: 0.5x(1+tanh(sqrt(2/pi)(x+0.044715x^3)))
  float x3 = x * x * x;
  float t = tanhf(0.7978845608028654f * (x + 0.044715f * x3));
  return 0.5f * x * (1.0f + t);
}

__device__ __forceinline__ void split_bf16(float v, __hip_bfloat16& hi, __hip_bfloat16& lo) {
  hi = __float2bfloat16(v);
  lo = __float2bfloat16(v - __bfloat162float(hi));
}

// ---------------- CSR build: once per batch (was duplicated per chunk) ------
template<int NN>
__global__ __launch_bounds__(256)
void csr_build_kernel(const int* __restrict__ src_base, int src_stride,
                      const int* __restrict__ dst_base, int dst_stride,
                      int* __restrict__ g_rs,    // [BATCH][NN+1]
                      int* __restrict__ g_ids) { // [BATCH][NEDGE] (valid prefix)
  __shared__ int s_cnt[NN];          // counts, then fill cursor
  __shared__ int s_rs[NN + 1];       // CSR row starts
  __shared__ int s_csr[NEDGE];       // src ids grouped by dst
  const int b = blockIdx.x;
  const int tid = threadIdx.x;
  const int* se = src_base + (size_t)b * src_stride;
  const int* de = dst_base + (size_t)b * dst_stride;
  if (tid < NN) s_cnt[tid] = 0;
  __syncthreads();
  // pass 1: in-degree counts (invalid edges have src<0)
  for (int e = tid; e < NEDGE; e += 256) {
    int s = se[e];
    if (s >= 0) atomicAdd(&s_cnt[de[e]], 1);
  }
  __syncthreads();
  // inclusive Hillis-Steele scan over NN counts
  if (tid < NN) s_rs[tid] = s_cnt[tid];
  __syncthreads();
  for (int off = 1; off < NN; off <<= 1) {
    int add = 0;
    if (tid < NN && tid >= off) add = s_rs[tid - off];
    __syncthreads();
    if (tid < NN) s_rs[tid] += add;
    __syncthreads();
  }
  int incl = (tid < NN) ? s_rs[tid] : 0;
  __syncthreads();
  if (tid < NN) s_rs[tid + 1] = incl;
  if (tid == 0) s_rs[0] = 0;
  if (tid < NN) s_cnt[tid] = 0;
  __syncthreads();
  // pass 2: scatter src ids into CSR order
  for (int e = tid; e < NEDGE; e += 256) {
    int s = se[e];
    if (s >= 0) {
      int d = de[e];
      int p = s_rs[d] + atomicAdd(&s_cnt[d], 1);
      s_csr[p] = s;
    }
  }
  __syncthreads();
  const int total = s_rs[NN];
  for (int i = tid; i <= NN; i += 256) g_rs[b * (NN + 1) + i] = s_rs[i];
  for (int i = tid; i < total; i += 256) g_ids[b * NEDGE + i] = s_csr[i];
}

// ---------------- GIN gather: h = x + sum(x[src]) per dst, split-bf16 out ---
// Grid (BATCH, FF/32). CSR staged from global into LDS (~17.5 KB -> 8 blk/CU).
template<int NN, int FF>
__global__ __launch_bounds__(256)
void gin_gather_kernel(const float* __restrict__ x,
                       const int* __restrict__ g_rs, const int* __restrict__ g_ids,
                       __hip_bfloat16* __restrict__ Hhi,
                       __hip_bfloat16* __restrict__ Hlo) {
  constexpr int LPE = 8;             // 8 lanes x float4 = 32 cols/block
  constexpr int GRP = 256 / LPE;     // 32 rows accumulated in parallel
  constexpr int F4 = FF / 4;
  __shared__ int s_rs[NN + 1];
  __shared__ int s_ids[NEDGE];
  const int b = blockIdx.x;
  const int chunk = blockIdx.y;
  const int tid = threadIdx.x;
  for (int i = tid; i <= NN; i += 256) s_rs[i] = g_rs[b * (NN + 1) + i];
  __syncthreads();
  const int total = s_rs[NN];
  for (int i = tid; i < total; i += 256) s_ids[i] = g_ids[b * NEDGE + i];
  __syncthreads();
  const int lane = tid & (LPE - 1);
  const int grp = tid / LPE;
  const int cb = chunk * LPE;        // float4 column base
  const float4* x4 = (const float4*)x + (size_t)b * NN * F4;
  for (int d = grp; d < NN; d += GRP) {
    int j0 = s_rs[d], j1 = s_rs[d + 1];
    float4 acc = x4[(size_t)d * F4 + cb + lane];
    for (int j = j0; j < j1; ++j) {
      int s = s_ids[j];
      float4 xv = x4[(size_t)s * F4 + cb + lane];
      acc.x += xv.x; acc.y += xv.y; acc.z += xv.z; acc.w += xv.w;
    }
    float av[4] = {acc.x, acc.y, acc.z, acc.w};
    union { __hip_bfloat16 h[4]; uint2 u; } hv, lv;   // aligned views
#pragma unroll
    for (int j = 0; j < 4; ++j) split_bf16(av[j], hv.h[j], lv.h[j]);
    size_t eo = ((size_t)b * NN + d) * FF + (cb + lane) * 4;
    *(uint2*)&Hhi[eo] = hv.u;
    *(uint2*)&Hlo[eo] = lv.u;
  }
}

// ---------------- weight transpose + split: W[K][256] -> Wt{hi,lo}[256][K] --
template<int K>
__global__ __launch_bounds__(256)
void wsplit_kernel(const float* __restrict__ W,
                   __hip_bfloat16* __restrict__ Whi, __hip_bfloat16* __restrict__ Wlo) {
  int idx = blockIdx.x * 256 + threadIdx.x;   // over 256*K outputs
  int c = idx / K, k = idx % K;               // K pow2, compile-time
  float w = W[(size_t)k * 256 + c];
  __hip_bfloat16 hi, lo;
  split_bf16(w, hi, lo);
  Whi[idx] = hi;   // idx == c*K + k
  Wlo[idx] = lo;
}

// ---------------- MFMA GEMM: C[M,256] = A[M,K] @ W[K,256] + b ---------------
// Split-bf16 3-product emulation (~fp32 precision). No LDS: fragments load
// direct from global; W^T-split is L2-resident. Block 256 thr = 4 waves (2x2),
// wave tile 64x64 = 4x4 frags of 16x16x32. MODE 0: f32 out; 1: gelu+split out.
template<int K, int MODE>
__global__ __launch_bounds__(256)
void mfma_gemm_kernel(const __hip_bfloat16* __restrict__ Ahi,
                      const __hip_bfloat16* __restrict__ Alo,
                      const __hip_bfloat16* __restrict__ Bhi,  // [256][K] = W^T
                      const __hip_bfloat16* __restrict__ Blo,
                      const float* __restrict__ bias,
                      float* __restrict__ Cf,
                      __hip_bfloat16* __restrict__ Chi,
                      __hip_bfloat16* __restrict__ Clo) {
  const int tid = threadIdx.x;
  const int wid = tid >> 6, lane = tid & 63;
  const int wr = wid >> 1, wc = wid & 1;
  const int lr = lane & 15, lg = lane >> 4;
  const int rowBase = blockIdx.x * 128 + wr * 64;
  const int colBase = blockIdx.y * 128 + wc * 64;
  float4v acc[4][4];
#pragma unroll
  for (int m = 0; m < 4; ++m)
#pragma unroll
    for (int n = 0; n < 4; ++n) acc[m][n] = (float4v){0.f, 0.f, 0.f, 0.f};
#pragma unroll 2
  for (int k0 = 0; k0 < K; k0 += 32) {
    short8v ah[4], al[4], bh[4], bl[4];
#pragma unroll
    for (int m = 0; m < 4; ++m) {
      size_t off = (size_t)(rowBase + m * 16 + lr) * K + k0 + lg * 8;
      ah[m] = *(const short8v*)(Ahi + off);
      al[m] = *(const short8v*)(Alo + off);
    }
#pragma unroll
    for (int n = 0; n < 4; ++n) {
      size_t off = (size_t)(colBase + n * 16 + lr) * K + k0 + lg * 8;
      bh[n] = *(const short8v*)(Bhi + off);
      bl[n] = *(const short8v*)(Blo + off);
    }
#pragma unroll
    for (int m = 0; m < 4; ++m)
#pragma unroll
      for (int n = 0; n < 4; ++n) {
        acc[m][n] = __builtin_amdgcn_mfma_f32_16x16x32_bf16(ah[m], bh[n], acc[m][n], 0, 0, 0);
        acc[m][n] = __builtin_amdgcn_mfma_f32_16x16x32_bf16(al[m], bh[n], acc[m][n], 0, 0, 0);
        acc[m][n] = __builtin_amdgcn_mfma_f32_16x16x32_bf16(ah[m], bl[n], acc[m][n], 0, 0, 0);
      }
  }
  // epilogue: C/D frag map (m89-verified): col = lane&15, row = (lane>>4)*4 + i
#pragma unroll
  for (int n = 0; n < 4; ++n) {
    const int col = colBase + n * 16 + lr;
    const float bv = bias[col];
#pragma unroll
    for (int m = 0; m < 4; ++m) {
      const int row0 = rowBase + m * 16 + lg * 4;
#pragma unroll
      for (int i = 0; i < 4; ++i) {
        float o = acc[m][n][i] + bv;
        if (MODE == 1) {
          o = gelu_f(o);
          __hip_bfloat16 hi, lo;
          split_bf16(o, hi, lo);
          Chi[(size_t)(row0 + i) * 256 + col] = hi;
          Clo[(size_t)(row0 + i) * 256 + col] = lo;
        } else {
          Cf[(size_t)(row0 + i) * 256 + col] = o;
        }
      }
    }
  }
}

// ---------------- BN stats: two-stage deterministic reduction ---------------
#define BN_PBLKS 1024
__global__ __launch_bounds__(256)
void bn_partial_kernel(const float* __restrict__ y, int M,
                       double* __restrict__ P1, double* __restrict__ P2) {
  const int c = threadIdx.x;
  double s = 0.0, s2 = 0.0;
  for (int r = blockIdx.x; r < M; r += BN_PBLKS) {
    float v = y[(size_t)r * 256 + c];
    s += (double)v;
    s2 += (double)v * (double)v;
  }
  P1[blockIdx.x * 256 + c] = s;
  P2[blockIdx.x * 256 + c] = s2;
}

// stats layout: [0..255]=mean, [256..511]=rsqrt(var+eps), [512]=1/||pw||
__global__ __launch_bounds__(256)
void bn_finalize_kernel(const double* __restrict__ P1, const double* __restrict__ P2,
                        int M, const float* __restrict__ pw, float* __restrict__ stats) {
  const int c = threadIdx.x;
  double s = 0.0, s2 = 0.0;
  for (int i = 0; i < BN_PBLKS; ++i) { s += P1[i * 256 + c]; s2 += P2[i * 256 + c]; }
  double mean = s / (double)M;
  double var = s2 / (double)M - mean * mean;
  stats[c] = (float)mean;
  stats[256 + c] = (float)(1.0 / sqrt(var + 1e-5));
  float w = pw[c];
  __shared__ float red[256];
  red[c] = w * w;
  __syncthreads();
  for (int off = 128; off; off >>= 1) {
    if (c < off) red[c] += red[c + off];
    __syncthreads();
  }
  if (c == 0) stats[512] = rsqrtf(red[0]);
}

// ---------------- score[row] = dot(gelu(bn(y[row])), pw) / ||pw|| -----------
#define SC_ROWS 16
__global__ __launch_bounds__(256)
void score_kernel(const float* __restrict__ y, const float* __restrict__ stats,
                  const float* __restrict__ gamma, const float* __restrict__ beta,
                  const float* __restrict__ pw, float* __restrict__ scores) {
  const int tid = threadIdx.x;
  const int lane = tid & 63, wid = tid >> 6;
  const float4 mean = ((const float4*)stats)[lane];
  const float4 inv = ((const float4*)(stats + 256))[lane];
  const float4 ga = ((const float4*)gamma)[lane];
  const float4 be = ((const float4*)beta)[lane];
  const float4 w = ((const float4*)pw)[lane];
  const float invn = stats[512];
#pragma unroll
  for (int i = 0; i < SC_ROWS / 4; ++i) {
    const int row = blockIdx.x * SC_ROWS + wid + 4 * i;
    float4 v = ((const float4*)y)[(size_t)row * 64 + lane];
    float p = gelu_f((v.x - mean.x) * inv.x * ga.x + be.x) * w.x
            + gelu_f((v.y - mean.y) * inv.y * ga.y + be.y) * w.y
            + gelu_f((v.z - mean.z) * inv.z * ga.z + be.z) * w.z
            + gelu_f((v.w - mean.w) * inv.w * ga.w + be.w) * w.w;
    p *= invn;
#pragma unroll
    for (int off = 32; off; off >>= 1) p += __shfl_xor(p, off, 64);
    if (lane == 0) scores[row] = p;
  }
}

// ---------------- top-k pool + readout + edge remap (block per batch) -------
__global__ __launch_bounds__(256)
void pool_kernel(const float* __restrict__ y, const float* __restrict__ scores,
                 const float* __restrict__ stats, const float* __restrict__ gamma,
                 const float* __restrict__ beta,
                 const int* __restrict__ src_in, int src_stride,
                 const int* __restrict__ dst_in, int dst_stride,
                 int* __restrict__ src_out, int* __restrict__ dst_out,
                 float* __restrict__ xnext, float* __restrict__ total,
                 int n, int k, int accumulate) {
  const int b = blockIdx.x;
  const int tid = threadIdx.x;
  __shared__ float s_sc[256];
  __shared__ float s_tv[256];
  __shared__ int s_map[256];
  if (tid < n) {
    float si = scores[b * n + tid];
    s_sc[tid] = si;
    s_tv[tid] = tanhf(si);
  }
  __syncthreads();
  if (tid < n) {
    // rank = #nodes strictly ahead (ties: lower index first, matches lax.top_k)
    float si = s_sc[tid];
    int r = 0;
    for (int j = 0; j < n; ++j) {
      float sj = s_sc[j];
      r += (sj > si) || (sj == si && j < tid);
    }
    s_map[tid] = (r < k) ? r : -1;
  }
  __syncthreads();
  const int c = tid;
  const float mean = stats[c], inv = stats[256 + c], ga = gamma[c], be = beta[c];
  float mx = -INFINITY, sm = 0.f;
  for (int i = 0; i < n; ++i) {
    int r = s_map[i];
    if (r < 0) continue;
    float v = y[((size_t)b * n + i) * 256 + c];
    float xp = gelu_f((v - mean) * inv * ga + be);
    float o = xp * s_tv[i];
    xnext[((size_t)b * k + r) * 256 + c] = o;
    mx = fmaxf(mx, o);
    sm += o;
  }
  float* tb = total + b * 512;
  float aval = sm / (float)k;
  if (accumulate) { tb[c] += mx; tb[256 + c] += aval; }
  else            { tb[c] = mx;  tb[256 + c] = aval; }
  const int* se = src_in + (size_t)b * src_stride;
  const int* de = dst_in + (size_t)b * dst_stride;
  int* so = src_out + (size_t)b * NEDGE;
  int* dq = dst_out + (size_t)b * NEDGE;
  for (int e = tid; e < NEDGE; e += 256) {
    int s = se[e], d = de[e];
    int ns = -1, nd = -1;
    if (s >= 0 && d >= 0) {
      ns = s_map[s];
      nd = s_map[d];
      if (ns < 0 || nd < 0) { ns = -1; nd = -1; }
    }
    so[e] = ns;
    dq[e] = nd;
  }
}

// ---------------- out = total @ Wlin + blin ---------------------------------
__global__ __launch_bounds__(256)
void final_linear_kernel(const float* __restrict__ total, const float* __restrict__ Wlin,
                         const float* __restrict__ blin, float* __restrict__ out) {
  const int b = blockIdx.x, o = threadIdx.x;
  __shared__ float tl[512];
  tl[o] = total[b * 512 + o];
  tl[256 + o] = total[b * 512 + 256 + o];
  __syncthreads();
  float acc = blin[o];
  for (int cc = 0; cc < 512; ++cc) acc += tl[cc] * Wlin[cc * 256 + o];
  out[b * 256 + o] = acc;
}

// ---------------- per-layer driver ------------------------------------------
template<int NN, int FF>
static void run_layer(const float* xin,
                      const int* src_in, int sstr, const int* dst_in, int dstr,
                      int* src_out, int* dst_out,
                      const float* const* P,  // W1,b1,W2,b2,gamma,beta,pw
                      int* g_rs, int* g_ids,
                      __hip_bfloat16* Ahi, __hip_bfloat16* Alo,
                      __hip_bfloat16* Thi, __hip_bfloat16* Tlo,
                      __hip_bfloat16* W1hi, __hip_bfloat16* W1lo,
                      __hip_bfloat16* W2hi, __hip_bfloat16* W2lo,
                      float* y, float* scores, float* stats,
                      double* P1, double* P2,
                      float* xnext, float* total, int accumulate,
                      hipStream_t stream) {
  constexpr int M = BATCH * NN;
  csr_build_kernel<NN><<<BATCH, 256, 0, stream>>>(src_in, sstr, dst_in, dstr, g_rs, g_ids);
  gin_gather_kernel<NN, FF><<<dim3(BATCH, FF / 32), 256, 0, stream>>>(
      xin, g_rs, g_ids, Ahi, Alo);
  wsplit_kernel<FF><<<FF, 256, 0, stream>>>(P[0], W1hi, W1lo);
  wsplit_kernel<256><<<256, 256, 0, stream>>>(P[2], W2hi, W2lo);
  mfma_gemm_kernel<FF, 1><<<dim3(M / 128, 2), 256, 0, stream>>>(
      Ahi, Alo, W1hi, W1lo, P[1], nullptr, Thi, Tlo);
  mfma_gemm_kernel<256, 0><<<dim3(M / 128, 2), 256, 0, stream>>>(
      Thi, Tlo, W2hi, W2lo, P[3], y, nullptr, nullptr);
  bn_partial_kernel<<<BN_PBLKS, 256, 0, stream>>>(y, M, P1, P2);
  bn_finalize_kernel<<<1, 256, 0, stream>>>(P1, P2, M, P[6], stats);
  score_kernel<<<M / SC_ROWS, 256, 0, stream>>>(y, stats, P[4], P[5], P[6], scores);
  pool_kernel<<<BATCH, 256, 0, stream>>>(y, scores, stats, P[4], P[5],
                                         src_in, sstr, dst_in, dstr, src_out, dst_out,
                                         xnext, total, NN, NN / 2, accumulate);
}

extern "C" void kernel_launch(void* const* d_in, const int* in_sizes, int n_in,
                              void* d_out, int out_size, void* d_ws, size_t ws_size,
                              hipStream_t stream) {
  (void)in_sizes; (void)n_in; (void)out_size; (void)ws_size;
  const float* x0 = (const float*)d_in[0];
  const int* ei = (const int*)d_in[1];
  const float* Wlin = (const float*)d_in[30];
  const float* blin = (const float*)d_in[31];
  const float* Lp[4][7];
  for (int l = 0; l < 4; ++l)
    for (int j = 0; j < 7; ++j)
      Lp[l][j] = (const float*)d_in[2 + l * 7 + j];

  char* ws = (char*)d_ws;
  size_t off = 0;
  auto alloc = [&](size_t bytes) -> void* {
    void* p = ws + off;
    off += (bytes + 255) & ~(size_t)255;
    return p;
  };
  float* xA = (float*)alloc((size_t)BATCH * 128 * 256 * 4);        // pooled x
  float* y = (float*)alloc((size_t)BATCH * 256 * 256 * 4);         // gemm2 out
  __hip_bfloat16* Ahi = (__hip_bfloat16*)alloc((size_t)8388608 * 2);
  __hip_bfloat16* Alo = (__hip_bfloat16*)alloc((size_t)8388608 * 2);
  __hip_bfloat16* Thi = (__hip_bfloat16*)alloc((size_t)BATCH * 256 * 256 * 2);
  __hip_bfloat16* Tlo = (__hip_bfloat16*)alloc((size_t)BATCH * 256 * 256 * 2);
  __hip_bfloat16* W1hi = (__hip_bfloat16*)alloc((size_t)256 * 256 * 2);
  __hip_bfloat16* W1lo = (__hip_bfloat16*)alloc((size_t)256 * 256 * 2);
  __hip_bfloat16* W2hi = (__hip_bfloat16*)alloc((size_t)256 * 256 * 2);
  __hip_bfloat16* W2lo = (__hip_bfloat16*)alloc((size_t)256 * 256 * 2);
  float* scores = (float*)alloc((size_t)BATCH * 256 * 4);
  float* stats = (float*)alloc(4096);
  double* P1 = (double*)alloc((size_t)BN_PBLKS * 256 * 8);
  double* P2 = (double*)alloc((size_t)BN_PBLKS * 256 * 8);
  int* es0 = (int*)alloc((size_t)BATCH * NEDGE * 4);
  int* ed0 = (int*)alloc((size_t)BATCH * NEDGE * 4);
  int* es1 = (int*)alloc((size_t)BATCH * NEDGE * 4);
  int* ed1 = (int*)alloc((size_t)BATCH * NEDGE * 4);
  int* g_rs = (int*)alloc((size_t)BATCH * 257 * 4);
  int* g_ids = (int*)alloc((size_t)BATCH * NEDGE * 4);
  float* total = (float*)alloc((size_t)BATCH * 512 * 4);

  // layer 1: n=256, F=128; edges straight from edge_index (B,2,E)
  run_layer<256, 128>(x0, ei, 2 * NEDGE, ei + NEDGE, 2 * NEDGE, es0, ed0,
                      Lp[0], g_rs, g_ids, Ahi, Alo, Thi, Tlo, W1hi, W1lo, W2hi, W2lo,
                      y, scores, stats, P1, P2, xA, total, 0, stream);
  // layer 2: n=128, F=256
  run_layer<128, 256>(xA, es0, NEDGE, ed0, NEDGE, es1, ed1,
                      Lp[1], g_rs, g_ids, Ahi, Alo, Thi, Tlo, W1hi, W1lo, W2hi, W2lo,
                      y, scores, stats, P1, P2, xA, total, 1, stream);
  // layer 3: n=64, F=256
  run_layer<64, 256>(xA, es1, NEDGE, ed1, NEDGE, es0, ed0,
                     Lp[2], g_rs, g_ids, Ahi, Alo, Thi, Tlo, W1hi, W1lo, W2hi, W2lo,
                     y, scores, stats, P1, P2, xA, total, 1, stream);
  // layer 4: n=32, F=256
  run_layer<32, 256>(xA, es0, NEDGE, ed0, NEDGE, es1, ed1,
                     Lp[3], g_rs, g_ids, Ahi, Alo, Thi, Tlo, W1hi, W1lo, W2hi, W2lo,
                     y, scores, stats, P1, P2, xA, total, 1, stream);

  final_linear_kernel<<<BATCH, 256, 0, stream>>>(total, Wlin, blin, (float*)d_out);
}

// Round 10
// 875.117 us; speedup vs baseline: 1.2984x; 1.2984x over previous
//
#include <hip/hip_runtime.h>
#include <hip/hip_bf16.h>
#include <math.h>

#define BATCH 256
#define NEDGE 4096
#define HDIM 256

typedef __attribute__((ext_vector_type(8))) short short8v;   // 8 bf16 = 4 VGPR
typedef __attribute__((ext_vector_type(4))) float float4v;

__device__ __forceinline__ float gelu_f(float x) {
  // jax.nn.gelu approximate=True: 0.5x(1+tanh(sqrt(2/pi)(x+0.044715x^3)))
  float x3 = x * x * x;
  float t = tanhf(0.7978845608028654f * (x + 0.044715f * x3));
  return 0.5f * x * (1.0f + t);
}

__device__ __forceinline__ void split_bf16(float v, __hip_bfloat16& hi, __hip_bfloat16& lo) {
  hi = __float2bfloat16(v);
  lo = __float2bfloat16(v - __bfloat162float(hi));
}

// ---------------- CSR build: once per batch ---------------------------------
template<int NN>
__global__ __launch_bounds__(256)
void csr_build_kernel(const int* __restrict__ src_base, int src_stride,
                      const int* __restrict__ dst_base, int dst_stride,
                      int* __restrict__ g_rs,    // [BATCH][NN+1]
                      int* __restrict__ g_ids) { // [BATCH][NEDGE] (valid prefix)
  __shared__ int s_cnt[NN];          // counts, then fill cursor
  __shared__ int s_rs[NN + 1];       // CSR row starts
  __shared__ int s_csr[NEDGE];       // src ids grouped by dst
  const int b = blockIdx.x;
  const int tid = threadIdx.x;
  const int* se = src_base + (size_t)b * src_stride;
  const int* de = dst_base + (size_t)b * dst_stride;
  if (tid < NN) s_cnt[tid] = 0;
  __syncthreads();
  for (int e = tid; e < NEDGE; e += 256) {
    int s = se[e];
    if (s >= 0) atomicAdd(&s_cnt[de[e]], 1);
  }
  __syncthreads();
  if (tid < NN) s_rs[tid] = s_cnt[tid];
  __syncthreads();
  for (int off = 1; off < NN; off <<= 1) {
    int add = 0;
    if (tid < NN && tid >= off) add = s_rs[tid - off];
    __syncthreads();
    if (tid < NN) s_rs[tid] += add;
    __syncthreads();
  }
  int incl = (tid < NN) ? s_rs[tid] : 0;
  __syncthreads();
  if (tid < NN) s_rs[tid + 1] = incl;
  if (tid == 0) s_rs[0] = 0;
  if (tid < NN) s_cnt[tid] = 0;
  __syncthreads();
  for (int e = tid; e < NEDGE; e += 256) {
    int s = se[e];
    if (s >= 0) {
      int d = de[e];
      int p = s_rs[d] + atomicAdd(&s_cnt[d], 1);
      s_csr[p] = s;
    }
  }
  __syncthreads();
  const int total = s_rs[NN];
  for (int i = tid; i <= NN; i += 256) g_rs[b * (NN + 1) + i] = s_rs[i];
  for (int i = tid; i < total; i += 256) g_ids[b * NEDGE + i] = s_csr[i];
}

// ---------------- GIN gather: h = x + sum(x[src]) per dst, split-bf16 out ---
template<int NN, int FF>
__global__ __launch_bounds__(256)
void gin_gather_kernel(const float* __restrict__ x,
                       const int* __restrict__ g_rs, const int* __restrict__ g_ids,
                       __hip_bfloat16* __restrict__ Hhi,
                       __hip_bfloat16* __restrict__ Hlo) {
  constexpr int LPE = 8;             // 8 lanes x float4 = 32 cols/block
  constexpr int GRP = 256 / LPE;     // 32 rows accumulated in parallel
  constexpr int F4 = FF / 4;
  __shared__ int s_rs[NN + 1];
  __shared__ int s_ids[NEDGE];
  const int b = blockIdx.x;
  const int chunk = blockIdx.y;
  const int tid = threadIdx.x;
  for (int i = tid; i <= NN; i += 256) s_rs[i] = g_rs[b * (NN + 1) + i];
  __syncthreads();
  const int total = s_rs[NN];
  for (int i = tid; i < total; i += 256) s_ids[i] = g_ids[b * NEDGE + i];
  __syncthreads();
  const int lane = tid & (LPE - 1);
  const int grp = tid / LPE;
  const int cb = chunk * LPE;        // float4 column base
  const float4* x4 = (const float4*)x + (size_t)b * NN * F4;
  for (int d = grp; d < NN; d += GRP) {
    int j0 = s_rs[d], j1 = s_rs[d + 1];
    float4 acc = x4[(size_t)d * F4 + cb + lane];
    for (int j = j0; j < j1; ++j) {
      int s = s_ids[j];
      float4 xv = x4[(size_t)s * F4 + cb + lane];
      acc.x += xv.x; acc.y += xv.y; acc.z += xv.z; acc.w += xv.w;
    }
    float av[4] = {acc.x, acc.y, acc.z, acc.w};
    union { __hip_bfloat16 h[4]; uint2 u; } hv, lv;   // aligned views
#pragma unroll
    for (int j = 0; j < 4; ++j) split_bf16(av[j], hv.h[j], lv.h[j]);
    size_t eo = ((size_t)b * NN + d) * FF + (cb + lane) * 4;
    *(uint2*)&Hhi[eo] = hv.u;
    *(uint2*)&Hlo[eo] = lv.u;
  }
}

// ---------------- weight transpose + split: W[K][256] -> Wt{hi,lo}[256][K] --
template<int K>
__global__ __launch_bounds__(256)
void wsplit_kernel(const float* __restrict__ W,
                   __hip_bfloat16* __restrict__ Whi, __hip_bfloat16* __restrict__ Wlo) {
  int idx = blockIdx.x * 256 + threadIdx.x;   // over 256*K outputs
  int c = idx / K, k = idx % K;               // K pow2, compile-time
  float w = W[(size_t)k * 256 + c];
  __hip_bfloat16 hi, lo;
  split_bf16(w, hi, lo);
  Whi[idx] = hi;   // idx == c*K + k
  Wlo[idx] = lo;
}

// ---------------- MFMA GEMM: C[M,256] = A[M,K] @ W[K,256] + b ---------------
// Split-bf16 3-product emulation (~fp32 precision). No LDS: fragments load
// direct from global; W^T-split is L2-resident. Block 256 thr = 4 waves (2x2),
// wave tile 64x64 = 4x4 frags of 16x16x32. MODE 0: f32 out; 1: gelu+split out.
template<int K, int MODE>
__global__ __launch_bounds__(256)
void mfma_gemm_kernel(const __hip_bfloat16* __restrict__ Ahi,
                      const __hip_bfloat16* __restrict__ Alo,
                      const __hip_bfloat16* __restrict__ Bhi,  // [256][K] = W^T
                      const __hip_bfloat16* __restrict__ Blo,
                      const float* __restrict__ bias,
                      float* __restrict__ Cf,
                      __hip_bfloat16* __restrict__ Chi,
                      __hip_bfloat16* __restrict__ Clo) {
  const int tid = threadIdx.x;
  const int wid = tid >> 6, lane = tid & 63;
  const int wr = wid >> 1, wc = wid & 1;
  const int lr = lane & 15, lg = lane >> 4;
  const int rowBase = blockIdx.x * 128 + wr * 64;
  const int colBase = blockIdx.y * 128 + wc * 64;
  float4v acc[4][4];
#pragma unroll
  for (int m = 0; m < 4; ++m)
#pragma unroll
    for (int n = 0; n < 4; ++n) acc[m][n] = (float4v){0.f, 0.f, 0.f, 0.f};
#pragma unroll 2
  for (int k0 = 0; k0 < K; k0 += 32) {
    short8v ah[4], al[4], bh[4], bl[4];
#pragma unroll
    for (int m = 0; m < 4; ++m) {
      size_t off = (size_t)(rowBase + m * 16 + lr) * K + k0 + lg * 8;
      ah[m] = *(const short8v*)(Ahi + off);
      al[m] = *(const short8v*)(Alo + off);
    }
#pragma unroll
    for (int n = 0; n < 4; ++n) {
      size_t off = (size_t)(colBase + n * 16 + lr) * K + k0 + lg * 8;
      bh[n] = *(const short8v*)(Bhi + off);
      bl[n] = *(const short8v*)(Blo + off);
    }
#pragma unroll
    for (int m = 0; m < 4; ++m)
#pragma unroll
      for (int n = 0; n < 4; ++n) {
        acc[m][n] = __builtin_amdgcn_mfma_f32_16x16x32_bf16(ah[m], bh[n], acc[m][n], 0, 0, 0);
        acc[m][n] = __builtin_amdgcn_mfma_f32_16x16x32_bf16(al[m], bh[n], acc[m][n], 0, 0, 0);
        acc[m][n] = __builtin_amdgcn_mfma_f32_16x16x32_bf16(ah[m], bl[n], acc[m][n], 0, 0, 0);
      }
  }
  // epilogue: C/D frag map (m89-verified): col = lane&15, row = (lane>>4)*4 + i
#pragma unroll
  for (int n = 0; n < 4; ++n) {
    const int col = colBase + n * 16 + lr;
    const float bv = bias[col];
#pragma unroll
    for (int m = 0; m < 4; ++m) {
      const int row0 = rowBase + m * 16 + lg * 4;
#pragma unroll
      for (int i = 0; i < 4; ++i) {
        float o = acc[m][n][i] + bv;
        if (MODE == 1) {
          o = gelu_f(o);
          __hip_bfloat16 hi, lo;
          split_bf16(o, hi, lo);
          Chi[(size_t)(row0 + i) * 256 + col] = hi;
          Clo[(size_t)(row0 + i) * 256 + col] = lo;
        } else {
          Cf[(size_t)(row0 + i) * 256 + col] = o;
        }
      }
    }
  }
}

// ---------------- BN stats: two-stage deterministic reduction ---------------
#define BN_PBLKS 1024
__global__ __launch_bounds__(256)
void bn_partial_kernel(const float* __restrict__ y, int M,
                       double* __restrict__ P1, double* __restrict__ P2) {
  const int c = threadIdx.x;
  double s = 0.0, s2 = 0.0;
  for (int r = blockIdx.x; r < M; r += BN_PBLKS) {
    float v = y[(size_t)r * 256 + c];
    s += (double)v;
    s2 += (double)v * (double)v;
  }
  P1[blockIdx.x * 256 + c] = s;
  P2[blockIdx.x * 256 + c] = s2;
}

// stats layout: [0..255]=mean, [256..511]=rsqrt(var+eps), [512]=1/||pw||
// grid 256 (one block per column), block 256.
__global__ __launch_bounds__(256)
void bn_finalize_kernel(const double* __restrict__ P1, const double* __restrict__ P2,
                        int M, const float* __restrict__ pw, float* __restrict__ stats) {
  const int c = blockIdx.x;
  const int tid = threadIdx.x;
  __shared__ double r1[256], r2[256];
  double s = 0.0, s2 = 0.0;
  for (int i = tid; i < BN_PBLKS; i += 256) {
    s += P1[i * 256 + c];
    s2 += P2[i * 256 + c];
  }
  r1[tid] = s; r2[tid] = s2;
  __syncthreads();
  for (int off = 128; off; off >>= 1) {
    if (tid < off) { r1[tid] += r1[tid + off]; r2[tid] += r2[tid + off]; }
    __syncthreads();
  }
  if (tid == 0) {
    double mean = r1[0] / (double)M;
    double var = r2[0] / (double)M - mean * mean;
    stats[c] = (float)mean;
    stats[256 + c] = (float)(1.0 / sqrt(var + 1e-5));
  }
  if (c == 0) {   // block 0 additionally reduces ||pw||^2
    __syncthreads();
    float w = pw[tid];
    r1[tid] = (double)w * (double)w;
    __syncthreads();
    for (int off = 128; off; off >>= 1) {
      if (tid < off) r1[tid] += r1[tid + off];
      __syncthreads();
    }
    if (tid == 0) stats[512] = (float)(1.0 / sqrt(r1[0]));
  }
}

// ---------------- score[row] = dot(gelu(bn(y[row])), pw) / ||pw|| -----------
#define SC_ROWS 16
__global__ __launch_bounds__(256)
void score_kernel(const float* __restrict__ y, const float* __restrict__ stats,
                  const float* __restrict__ gamma, const float* __restrict__ beta,
                  const float* __restrict__ pw, float* __restrict__ scores) {
  const int tid = threadIdx.x;
  const int lane = tid & 63, wid = tid >> 6;
  const float4 mean = ((const float4*)stats)[lane];
  const float4 inv = ((const float4*)(stats + 256))[lane];
  const float4 ga = ((const float4*)gamma)[lane];
  const float4 be = ((const float4*)beta)[lane];
  const float4 w = ((const float4*)pw)[lane];
  const float invn = stats[512];
#pragma unroll
  for (int i = 0; i < SC_ROWS / 4; ++i) {
    const int row = blockIdx.x * SC_ROWS + wid + 4 * i;
    float4 v = ((const float4*)y)[(size_t)row * 64 + lane];
    float p = gelu_f((v.x - mean.x) * inv.x * ga.x + be.x) * w.x
            + gelu_f((v.y - mean.y) * inv.y * ga.y + be.y) * w.y
            + gelu_f((v.z - mean.z) * inv.z * ga.z + be.z) * w.z
            + gelu_f((v.w - mean.w) * inv.w * ga.w + be.w) * w.w;
    p *= invn;
#pragma unroll
    for (int off = 32; off; off >>= 1) p += __shfl_xor(p, off, 64);
    if (lane == 0) scores[row] = p;
  }
}

// ---------------- top-k select + edge remap (block per batch) ---------------
__global__ __launch_bounds__(256)
void topk_kernel(const float* __restrict__ scores,
                 const int* __restrict__ src_in, int src_stride,
                 const int* __restrict__ dst_in, int dst_stride,
                 int* __restrict__ src_out, int* __restrict__ dst_out,
                 int* __restrict__ g_map, float* __restrict__ g_tanh,
                 int n, int k) {
  const int b = blockIdx.x;
  const int tid = threadIdx.x;
  __shared__ float s_sc[256];
  __shared__ int s_map[256];
  if (tid < n) s_sc[tid] = scores[b * n + tid];
  __syncthreads();
  if (tid < n) {
    // rank = #nodes strictly ahead (ties: lower index first, matches lax.top_k)
    float si = s_sc[tid];
    int r = 0;
    for (int j = 0; j < n; ++j) {
      float sj = s_sc[j];
      r += (sj > si) || (sj == si && j < tid);
    }
    int m = (r < k) ? r : -1;
    s_map[tid] = m;
    g_map[b * n + tid] = m;
    g_tanh[b * n + tid] = tanhf(si);
  }
  __syncthreads();
  const int* se = src_in + (size_t)b * src_stride;
  const int* de = dst_in + (size_t)b * dst_stride;
  int* so = src_out + (size_t)b * NEDGE;
  int* dq = dst_out + (size_t)b * NEDGE;
  for (int e = tid; e < NEDGE; e += 256) {
    int s = se[e], d = de[e];
    int ns = -1, nd = -1;
    if (s >= 0 && d >= 0) {
      ns = s_map[s];
      nd = s_map[d];
      if (ns < 0 || nd < 0) { ns = -1; nd = -1; }
    }
    so[e] = ns;
    dq[e] = nd;
  }
}

// ---------------- pool gather + readout: grid (BATCH, 8) --------------------
// Block owns 32 cols x all rows: xnext scatter + per-column max/mean readout.
__global__ __launch_bounds__(256)
void pool_gather_kernel(const float* __restrict__ y,
                        const int* __restrict__ g_map, const float* __restrict__ g_tanh,
                        const float* __restrict__ stats, const float* __restrict__ gamma,
                        const float* __restrict__ beta,
                        float* __restrict__ xnext, float* __restrict__ total,
                        int n, int k, int accumulate) {
  const int b = blockIdx.x, chunk = blockIdx.y;
  const int tid = threadIdx.x;
  const int lane = tid & 7;          // 8 float4 lanes = 32 cols
  const int grp = tid >> 3;          // 32 row-groups
  const int cb = chunk * 8;          // float4 column base
  const float4 mean = ((const float4*)stats)[cb + lane];
  const float4 inv = ((const float4*)(stats + 256))[cb + lane];
  const float4 ga = ((const float4*)gamma)[cb + lane];
  const float4 be = ((const float4*)beta)[cb + lane];
  const float4* y4 = (const float4*)y + (size_t)b * n * 64;
  float4* xn4 = (float4*)xnext + (size_t)b * k * 64;
  float4 mx = make_float4(-INFINITY, -INFINITY, -INFINITY, -INFINITY);
  float4 sm = make_float4(0.f, 0.f, 0.f, 0.f);
  for (int i = grp; i < n; i += 32) {
    int r = g_map[b * n + i];
    if (r < 0) continue;
    float tv = g_tanh[b * n + i];
    float4 v = y4[(size_t)i * 64 + cb + lane];
    float4 o;
    o.x = gelu_f((v.x - mean.x) * inv.x * ga.x + be.x) * tv;
    o.y = gelu_f((v.y - mean.y) * inv.y * ga.y + be.y) * tv;
    o.z = gelu_f((v.z - mean.z) * inv.z * ga.z + be.z) * tv;
    o.w = gelu_f((v.w - mean.w) * inv.w * ga.w + be.w) * tv;
    xn4[(size_t)r * 64 + cb + lane] = o;
    mx.x = fmaxf(mx.x, o.x); mx.y = fmaxf(mx.y, o.y);
    mx.z = fmaxf(mx.z, o.z); mx.w = fmaxf(mx.w, o.w);
    sm.x += o.x; sm.y += o.y; sm.z += o.z; sm.w += o.w;
  }
  // reduce over the 32 row-groups (stride multiples of 8 preserve lane)
  __shared__ float4 s_mx[256];
  __shared__ float4 s_sm[256];
  s_mx[tid] = mx; s_sm[tid] = sm;
  __syncthreads();
  for (int off = 128; off >= 8; off >>= 1) {
    if (tid < off) {
      float4 a = s_mx[tid], bb = s_mx[tid + off];
      a.x = fmaxf(a.x, bb.x); a.y = fmaxf(a.y, bb.y);
      a.z = fmaxf(a.z, bb.z); a.w = fmaxf(a.w, bb.w);
      s_mx[tid] = a;
      float4 c = s_sm[tid], d = s_sm[tid + off];
      c.x += d.x; c.y += d.y; c.z += d.z; c.w += d.w;
      s_sm[tid] = c;
    }
    __syncthreads();
  }
  if (tid < 8) {
    float4 fmx = s_mx[tid], fsm = s_sm[tid];
    float* tb = total + b * 512;
    const int cbase = chunk * 32 + tid * 4;
    const float invk = 1.f / (float)k;
    float mvals[4] = {fmx.x, fmx.y, fmx.z, fmx.w};
    float svals[4] = {fsm.x, fsm.y, fsm.z, fsm.w};
#pragma unroll
    for (int j = 0; j < 4; ++j) {
      float av = svals[j] * invk;
      if (accumulate) { tb[cbase + j] += mvals[j]; tb[256 + cbase + j] += av; }
      else            { tb[cbase + j] = mvals[j];  tb[256 + cbase + j] = av; }
    }
  }
}

// ---------------- out = total @ Wlin + blin ---------------------------------
__global__ __launch_bounds__(256)
void final_linear_kernel(const float* __restrict__ total, const float* __restrict__ Wlin,
                         const float* __restrict__ blin, float* __restrict__ out) {
  const int b = blockIdx.x, o = threadIdx.x;
  __shared__ float tl[512];
  tl[o] = total[b * 512 + o];
  tl[256 + o] = total[b * 512 + 256 + o];
  __syncthreads();
  float acc = blin[o];
  for (int cc = 0; cc < 512; ++cc) acc += tl[cc] * Wlin[cc * 256 + o];
  out[b * 256 + o] = acc;
}

// ---------------- per-layer driver ------------------------------------------
template<int NN, int FF>
static void run_layer(const float* xin,
                      const int* src_in, int sstr, const int* dst_in, int dstr,
                      int* src_out, int* dst_out,
                      const float* const* P,  // W1,b1,W2,b2,gamma,beta,pw
                      int* g_rs, int* g_ids, int* g_map, float* g_tanh,
                      __hip_bfloat16* Ahi, __hip_bfloat16* Alo,
                      __hip_bfloat16* Thi, __hip_bfloat16* Tlo,
                      __hip_bfloat16* W1hi, __hip_bfloat16* W1lo,
                      __hip_bfloat16* W2hi, __hip_bfloat16* W2lo,
                      float* y, float* scores, float* stats,
                      double* P1, double* P2,
                      float* xnext, float* total, int accumulate,
                      hipStream_t stream) {
  constexpr int M = BATCH * NN;
  csr_build_kernel<NN><<<BATCH, 256, 0, stream>>>(src_in, sstr, dst_in, dstr, g_rs, g_ids);
  gin_gather_kernel<NN, FF><<<dim3(BATCH, FF / 32), 256, 0, stream>>>(
      xin, g_rs, g_ids, Ahi, Alo);
  wsplit_kernel<FF><<<FF, 256, 0, stream>>>(P[0], W1hi, W1lo);
  wsplit_kernel<256><<<256, 256, 0, stream>>>(P[2], W2hi, W2lo);
  mfma_gemm_kernel<FF, 1><<<dim3(M / 128, 2), 256, 0, stream>>>(
      Ahi, Alo, W1hi, W1lo, P[1], nullptr, Thi, Tlo);
  mfma_gemm_kernel<256, 0><<<dim3(M / 128, 2), 256, 0, stream>>>(
      Thi, Tlo, W2hi, W2lo, P[3], y, nullptr, nullptr);
  bn_partial_kernel<<<BN_PBLKS, 256, 0, stream>>>(y, M, P1, P2);
  bn_finalize_kernel<<<256, 256, 0, stream>>>(P1, P2, M, P[6], stats);
  score_kernel<<<M / SC_ROWS, 256, 0, stream>>>(y, stats, P[4], P[5], P[6], scores);
  topk_kernel<<<BATCH, 256, 0, stream>>>(scores, src_in, sstr, dst_in, dstr,
                                         src_out, dst_out, g_map, g_tanh, NN, NN / 2);
  pool_gather_kernel<<<dim3(BATCH, 8), 256, 0, stream>>>(
      y, g_map, g_tanh, stats, P[4], P[5], xnext, total, NN, NN / 2, accumulate);
}

extern "C" void kernel_launch(void* const* d_in, const int* in_sizes, int n_in,
                              void* d_out, int out_size, void* d_ws, size_t ws_size,
                              hipStream_t stream) {
  (void)in_sizes; (void)n_in; (void)out_size; (void)ws_size;
  const float* x0 = (const float*)d_in[0];
  const int* ei = (const int*)d_in[1];
  const float* Wlin = (const float*)d_in[30];
  const float* blin = (const float*)d_in[31];
  const float* Lp[4][7];
  for (int l = 0; l < 4; ++l)
    for (int j = 0; j < 7; ++j)
      Lp[l][j] = (const float*)d_in[2 + l * 7 + j];

  char* ws = (char*)d_ws;
  size_t off = 0;
  auto alloc = [&](size_t bytes) -> void* {
    void* p = ws + off;
    off += (bytes + 255) & ~(size_t)255;
    return p;
  };
  float* xA = (float*)alloc((size_t)BATCH * 128 * 256 * 4);        // pooled x
  float* y = (float*)alloc((size_t)BATCH * 256 * 256 * 4);         // gemm2 out
  __hip_bfloat16* Ahi = (__hip_bfloat16*)alloc((size_t)8388608 * 2);
  __hip_bfloat16* Alo = (__hip_bfloat16*)alloc((size_t)8388608 * 2);
  __hip_bfloat16* Thi = (__hip_bfloat16*)alloc((size_t)BATCH * 256 * 256 * 2);
  __hip_bfloat16* Tlo = (__hip_bfloat16*)alloc((size_t)BATCH * 256 * 256 * 2);
  __hip_bfloat16* W1hi = (__hip_bfloat16*)alloc((size_t)256 * 256 * 2);
  __hip_bfloat16* W1lo = (__hip_bfloat16*)alloc((size_t)256 * 256 * 2);
  __hip_bfloat16* W2hi = (__hip_bfloat16*)alloc((size_t)256 * 256 * 2);
  __hip_bfloat16* W2lo = (__hip_bfloat16*)alloc((size_t)256 * 256 * 2);
  float* scores = (float*)alloc((size_t)BATCH * 256 * 4);
  float* stats = (float*)alloc(4096);
  double* P1 = (double*)alloc((size_t)BN_PBLKS * 256 * 8);
  double* P2 = (double*)alloc((size_t)BN_PBLKS * 256 * 8);
  int* es0 = (int*)alloc((size_t)BATCH * NEDGE * 4);
  int* ed0 = (int*)alloc((size_t)BATCH * NEDGE * 4);
  int* es1 = (int*)alloc((size_t)BATCH * NEDGE * 4);
  int* ed1 = (int*)alloc((size_t)BATCH * NEDGE * 4);
  int* g_rs = (int*)alloc((size_t)BATCH * 257 * 4);
  int* g_ids = (int*)alloc((size_t)BATCH * NEDGE * 4);
  int* g_map = (int*)alloc((size_t)BATCH * 256 * 4);
  float* g_tanh = (float*)alloc((size_t)BATCH * 256 * 4);
  float* total = (float*)alloc((size_t)BATCH * 512 * 4);

  // layer 1: n=256, F=128; edges straight from edge_index (B,2,E)
  run_layer<256, 128>(x0, ei, 2 * NEDGE, ei + NEDGE, 2 * NEDGE, es0, ed0,
                      Lp[0], g_rs, g_ids, g_map, g_tanh,
                      Ahi, Alo, Thi, Tlo, W1hi, W1lo, W2hi, W2lo,
                      y, scores, stats, P1, P2, xA, total, 0, stream);
  // layer 2: n=128, F=256
  run_layer<128, 256>(xA, es0, NEDGE, ed0, NEDGE, es1, ed1,
                      Lp[1], g_rs, g_ids, g_map, g_tanh,
                      Ahi, Alo, Thi, Tlo, W1hi, W1lo, W2hi, W2lo,
                      y, scores, stats, P1, P2, xA, total, 1, stream);
  // layer 3: n=64, F=256
  run_layer<64, 256>(xA, es1, NEDGE, ed1, NEDGE, es0, ed0,
                     Lp[2], g_rs, g_ids, g_map, g_tanh,
                     Ahi, Alo, Thi, Tlo, W1hi, W1lo, W2hi, W2lo,
                     y, scores, stats, P1, P2, xA, total, 1, stream);
  // layer 4: n=32, F=256
  run_layer<32, 256>(xA, es0, NEDGE, ed0, NEDGE, es1, ed1,
                     Lp[3], g_rs, g_ids, g_map, g_tanh,
                     Ahi, Alo, Thi, Tlo, W1hi, W1lo, W2hi, W2lo,
                     y, scores, stats, P1, P2, xA, total, 1, stream);

  final_linear_kernel<<<BATCH, 256, 0, stream>>>(total, Wlin, blin, (float*)d_out);
}

// Round 12
// 787.114 us; speedup vs baseline: 1.4435x; 1.1118x over previous
//
#include <hip/hip_runtime.h>
#include <hip/hip_bf16.h>
#include <math.h>

#define BATCH 256
#define NEDGE 4096
#define HDIM 256

typedef __attribute__((ext_vector_type(8))) short short8v;   // 8 bf16 = 4 VGPR
typedef __attribute__((ext_vector_type(4))) float float4v;

__device__ __forceinline__ float gelu_f(float x) {
  // jax.nn.gelu approximate=True: 0.5x(1+tanh(sqrt(2/pi)(x+0.044715x^3)))
  float x3 = x * x * x;
  float t = tanhf(0.7978845608028654f * (x + 0.044715f * x3));
  return 0.5f * x * (1.0f + t);
}

__device__ __forceinline__ void split_bf16(float v, __hip_bfloat16& hi, __hip_bfloat16& lo) {
  hi = __float2bfloat16(v);
  lo = __float2bfloat16(v - __bfloat162float(hi));
}

// ---------------- CSR build: once per batch ---------------------------------
template<int NN>
__global__ __launch_bounds__(256)
void csr_build_kernel(const int* __restrict__ src_base, int src_stride,
                      const int* __restrict__ dst_base, int dst_stride,
                      int* __restrict__ g_rs,    // [BATCH][NN+1]
                      int* __restrict__ g_ids) { // [BATCH][NEDGE] (valid prefix)
  __shared__ int s_cnt[NN];          // counts, then fill cursor
  __shared__ int s_rs[NN + 1];       // CSR row starts
  __shared__ int s_csr[NEDGE];       // src ids grouped by dst
  const int b = blockIdx.x;
  const int tid = threadIdx.x;
  const int* se = src_base + (size_t)b * src_stride;
  const int* de = dst_base + (size_t)b * dst_stride;
  if (tid < NN) s_cnt[tid] = 0;
  __syncthreads();
  for (int e = tid; e < NEDGE; e += 256) {
    int s = se[e];
    if (s >= 0) atomicAdd(&s_cnt[de[e]], 1);
  }
  __syncthreads();
  if (tid < NN) s_rs[tid] = s_cnt[tid];
  __syncthreads();
  for (int off = 1; off < NN; off <<= 1) {
    int add = 0;
    if (tid < NN && tid >= off) add = s_rs[tid - off];
    __syncthreads();
    if (tid < NN) s_rs[tid] += add;
    __syncthreads();
  }
  int incl = (tid < NN) ? s_rs[tid] : 0;
  __syncthreads();
  if (tid < NN) s_rs[tid + 1] = incl;
  if (tid == 0) s_rs[0] = 0;
  if (tid < NN) s_cnt[tid] = 0;
  __syncthreads();
  for (int e = tid; e < NEDGE; e += 256) {
    int s = se[e];
    if (s >= 0) {
      int d = de[e];
      int p = s_rs[d] + atomicAdd(&s_cnt[d], 1);
      s_csr[p] = s;
    }
  }
  __syncthreads();
  const int total = s_rs[NN];
  for (int i = tid; i <= NN; i += 256) g_rs[b * (NN + 1) + i] = s_rs[i];
  for (int i = tid; i < total; i += 256) g_ids[b * NEDGE + i] = s_csr[i];
}

// ---------------- GIN gather: h = x + sum(x[src]) per dst, split-bf16 out ---
// Grid (BATCH, FF/32, ZS). ZS splits rows for occupancy on the big layer.
template<int NN, int FF, int ZS>
__global__ __launch_bounds__(256)
void gin_gather_kernel(const float* __restrict__ x,
                       const int* __restrict__ g_rs, const int* __restrict__ g_ids,
                       __hip_bfloat16* __restrict__ Hhi,
                       __hip_bfloat16* __restrict__ Hlo) {
  constexpr int LPE = 8;             // 8 lanes x float4 = 32 cols/block
  constexpr int GRP = 256 / LPE;     // 32 rows accumulated in parallel
  constexpr int F4 = FF / 4;
  __shared__ int s_rs[NN + 1];
  __shared__ int s_ids[NEDGE];
  const int b = blockIdx.x;
  const int chunk = blockIdx.y;
  const int tid = threadIdx.x;
  for (int i = tid; i <= NN; i += 256) s_rs[i] = g_rs[b * (NN + 1) + i];
  __syncthreads();
  const int total = s_rs[NN];
  for (int i = tid; i < total; i += 256) s_ids[i] = g_ids[b * NEDGE + i];
  __syncthreads();
  const int lane = tid & (LPE - 1);
  const int grp = tid / LPE;
  const int cb = chunk * LPE;        // float4 column base
  const int r0 = blockIdx.z * (NN / ZS);
  const int r1 = r0 + NN / ZS;
  const float4* x4 = (const float4*)x + (size_t)b * NN * F4;
  for (int d = r0 + grp; d < r1; d += GRP) {
    int j0 = s_rs[d], j1 = s_rs[d + 1];
    float4 acc = x4[(size_t)d * F4 + cb + lane];
    for (int j = j0; j < j1; ++j) {
      int s = s_ids[j];
      float4 xv = x4[(size_t)s * F4 + cb + lane];
      acc.x += xv.x; acc.y += xv.y; acc.z += xv.z; acc.w += xv.w;
    }
    float av[4] = {acc.x, acc.y, acc.z, acc.w};
    union { __hip_bfloat16 h[4]; uint2 u; } hv, lv;   // aligned views
#pragma unroll
    for (int j = 0; j < 4; ++j) split_bf16(av[j], hv.h[j], lv.h[j]);
    size_t eo = ((size_t)b * NN + d) * FF + (cb + lane) * 4;
    *(uint2*)&Hhi[eo] = hv.u;
    *(uint2*)&Hlo[eo] = lv.u;
  }
}

// ---------------- weight transpose + split: W[K][256] -> Wt{hi,lo}[256][K] --
template<int K>
__global__ __launch_bounds__(256)
void wsplit_kernel(const float* __restrict__ W,
                   __hip_bfloat16* __restrict__ Whi, __hip_bfloat16* __restrict__ Wlo) {
  int idx = blockIdx.x * 256 + threadIdx.x;   // over 256*K outputs
  int c = idx / K, k = idx % K;               // K pow2, compile-time
  float w = W[(size_t)k * 256 + c];
  __hip_bfloat16 hi, lo;
  split_bf16(w, hi, lo);
  Whi[idx] = hi;   // idx == c*K + k
  Wlo[idx] = lo;
}

// ---------------- MFMA GEMM: C[M,256] = A[M,K] @ W[K,256] + b ---------------
// Split-bf16 3-product emulation (~fp32 precision). Block = 4 waves (2x2),
// wave tile 64x64 = 4x4 frags of 16x16x32. MODE 0: f32 out + fused BN column
// partial sums (per-block, deterministic); MODE 1: gelu + split-bf16 out.
template<int K, int MODE>
__global__ __launch_bounds__(256)
void mfma_gemm_kernel(const __hip_bfloat16* __restrict__ Ahi,
                      const __hip_bfloat16* __restrict__ Alo,
                      const __hip_bfloat16* __restrict__ Bhi,  // [256][K] = W^T
                      const __hip_bfloat16* __restrict__ Blo,
                      const float* __restrict__ bias,
                      float* __restrict__ Cf,
                      __hip_bfloat16* __restrict__ Chi,
                      __hip_bfloat16* __restrict__ Clo,
                      float* __restrict__ P1,   // [M/128][256] col partial sums
                      float* __restrict__ P2) { // [M/128][256] col partial sq-sums
  const int tid = threadIdx.x;
  const int wid = tid >> 6, lane = tid & 63;
  const int wr = wid >> 1, wc = wid & 1;
  const int lr = lane & 15, lg = lane >> 4;
  const int rowBase = blockIdx.x * 128 + wr * 64;
  const int colBase = blockIdx.y * 128 + wc * 64;
  float4v acc[4][4];
#pragma unroll
  for (int m = 0; m < 4; ++m)
#pragma unroll
    for (int n = 0; n < 4; ++n) acc[m][n] = (float4v){0.f, 0.f, 0.f, 0.f};
#pragma unroll 2
  for (int k0 = 0; k0 < K; k0 += 32) {
    short8v ah[4], al[4], bh[4], bl[4];
#pragma unroll
    for (int m = 0; m < 4; ++m) {
      size_t off = (size_t)(rowBase + m * 16 + lr) * K + k0 + lg * 8;
      ah[m] = *(const short8v*)(Ahi + off);
      al[m] = *(const short8v*)(Alo + off);
    }
#pragma unroll
    for (int n = 0; n < 4; ++n) {
      size_t off = (size_t)(colBase + n * 16 + lr) * K + k0 + lg * 8;
      bh[n] = *(const short8v*)(Bhi + off);
      bl[n] = *(const short8v*)(Blo + off);
    }
#pragma unroll
    for (int m = 0; m < 4; ++m)
#pragma unroll
      for (int n = 0; n < 4; ++n) {
        acc[m][n] = __builtin_amdgcn_mfma_f32_16x16x32_bf16(ah[m], bh[n], acc[m][n], 0, 0, 0);
        acc[m][n] = __builtin_amdgcn_mfma_f32_16x16x32_bf16(al[m], bh[n], acc[m][n], 0, 0, 0);
        acc[m][n] = __builtin_amdgcn_mfma_f32_16x16x32_bf16(ah[m], bl[n], acc[m][n], 0, 0, 0);
      }
  }
  // epilogue: C/D frag map (m89-verified): col = lane&15, row = (lane>>4)*4 + i
  float s1[4] = {0.f, 0.f, 0.f, 0.f};
  float s2[4] = {0.f, 0.f, 0.f, 0.f};
#pragma unroll
  for (int n = 0; n < 4; ++n) {
    const int col = colBase + n * 16 + lr;
    const float bv = bias[col];
#pragma unroll
    for (int m = 0; m < 4; ++m) {
      const int row0 = rowBase + m * 16 + lg * 4;
#pragma unroll
      for (int i = 0; i < 4; ++i) {
        float o = acc[m][n][i] + bv;
        if (MODE == 1) {
          o = gelu_f(o);
          __hip_bfloat16 hi, lo;
          split_bf16(o, hi, lo);
          Chi[(size_t)(row0 + i) * 256 + col] = hi;
          Clo[(size_t)(row0 + i) * 256 + col] = lo;
        } else {
          Cf[(size_t)(row0 + i) * 256 + col] = o;
          s1[n] += o;
          s2[n] += o * o;
        }
      }
    }
  }
  if constexpr (MODE == 0) {
    // per-block column sums: 8 threads share a column (wr x lg), 16 rows each
    __shared__ float r1[128][8];
    __shared__ float r2[128][8];
    const int slot = wr * 4 + lg;
#pragma unroll
    for (int n = 0; n < 4; ++n) {
      const int cidx = wc * 64 + n * 16 + lr;
      r1[cidx][slot] = s1[n];
      r2[cidx][slot] = s2[n];
    }
    __syncthreads();
    if (tid < 128) {
      float a = 0.f, b2 = 0.f;
#pragma unroll
      for (int j = 0; j < 8; ++j) { a += r1[tid][j]; b2 += r2[tid][j]; }
      size_t po = (size_t)blockIdx.x * 256 + blockIdx.y * 128 + tid;
      P1[po] = a;
      P2[po] = b2;
    }
  }
}

// ---------------- BN finalize: one block per column -------------------------
// stats layout: [0..255]=mean, [256..511]=rsqrt(var+eps), [512]=1/||pw||
__global__ __launch_bounds__(256)
void bn_finalize_kernel(const float* __restrict__ P1, const float* __restrict__ P2,
                        int M, int nblk, const float* __restrict__ pw,
                        float* __restrict__ stats) {
  const int c = blockIdx.x;
  const int tid = threadIdx.x;
  __shared__ double r1[256], r2[256];
  double s = 0.0, s2 = 0.0;
  for (int i = tid; i < nblk; i += 256) {
    s += (double)P1[i * 256 + c];
    s2 += (double)P2[i * 256 + c];
  }
  r1[tid] = s; r2[tid] = s2;
  __syncthreads();
  for (int off = 128; off; off >>= 1) {
    if (tid < off) { r1[tid] += r1[tid + off]; r2[tid] += r2[tid + off]; }
    __syncthreads();
  }
  if (tid == 0) {
    double mean = r1[0] / (double)M;
    double var = r2[0] / (double)M - mean * mean;
    stats[c] = (float)mean;
    stats[256 + c] = (float)(1.0 / sqrt(var + 1e-5));
  }
  if (c == 0) {   // block 0 additionally reduces ||pw||^2
    __syncthreads();
    float w = pw[tid];
    r1[tid] = (double)w * (double)w;
    __syncthreads();
    for (int off = 128; off; off >>= 1) {
      if (tid < off) r1[tid] += r1[tid + off];
      __syncthreads();
    }
    if (tid == 0) stats[512] = (float)(1.0 / sqrt(r1[0]));
  }
}

// ---------------- score[row] = dot(gelu(bn(y[row])), pw) / ||pw|| -----------
#define SC_ROWS 16
__global__ __launch_bounds__(256)
void score_kernel(const float* __restrict__ y, const float* __restrict__ stats,
                  const float* __restrict__ gamma, const float* __restrict__ beta,
                  const float* __restrict__ pw, float* __restrict__ scores) {
  const int tid = threadIdx.x;
  const int lane = tid & 63, wid = tid >> 6;
  const float4 mean = ((const float4*)stats)[lane];
  const float4 inv = ((const float4*)(stats + 256))[lane];
  const float4 ga = ((const float4*)gamma)[lane];
  const float4 be = ((const float4*)beta)[lane];
  const float4 w = ((const float4*)pw)[lane];
  const float invn = stats[512];
#pragma unroll
  for (int i = 0; i < SC_ROWS / 4; ++i) {
    const int row = blockIdx.x * SC_ROWS + wid + 4 * i;
    float4 v = ((const float4*)y)[(size_t)row * 64 + lane];
    float p = gelu_f((v.x - mean.x) * inv.x * ga.x + be.x) * w.x
            + gelu_f((v.y - mean.y) * inv.y * ga.y + be.y) * w.y
            + gelu_f((v.z - mean.z) * inv.z * ga.z + be.z) * w.z
            + gelu_f((v.w - mean.w) * inv.w * ga.w + be.w) * w.w;
    p *= invn;
#pragma unroll
    for (int off = 32; off; off >>= 1) p += __shfl_xor(p, off, 64);
    if (lane == 0) scores[row] = p;
  }
}

// ---------------- top-k select + edge remap (block per batch) ---------------
__global__ __launch_bounds__(256)
void topk_kernel(const float* __restrict__ scores,
                 const int* __restrict__ src_in, int src_stride,
                 const int* __restrict__ dst_in, int dst_stride,
                 int* __restrict__ src_out, int* __restrict__ dst_out,
                 int* __restrict__ g_map, float* __restrict__ g_tanh,
                 int n, int k) {
  const int b = blockIdx.x;
  const int tid = threadIdx.x;
  __shared__ float s_sc[256];
  __shared__ int s_map[256];
  if (tid < n) s_sc[tid] = scores[b * n + tid];
  __syncthreads();
  if (tid < n) {
    // rank = #nodes strictly ahead (ties: lower index first, matches lax.top_k)
    float si = s_sc[tid];
    int r = 0;
    for (int j = 0; j < n; ++j) {
      float sj = s_sc[j];
      r += (sj > si) || (sj == si && j < tid);
    }
    int m = (r < k) ? r : -1;
    s_map[tid] = m;
    g_map[b * n + tid] = m;
    g_tanh[b * n + tid] = tanhf(si);
  }
  __syncthreads();
  const int* se = src_in + (size_t)b * src_stride;
  const int* de = dst_in + (size_t)b * dst_stride;
  int* so = src_out + (size_t)b * NEDGE;
  int* dq = dst_out + (size_t)b * NEDGE;
  for (int e = tid; e < NEDGE; e += 256) {
    int s = se[e], d = de[e];
    int ns = -1, nd = -1;
    if (s >= 0 && d >= 0) {
      ns = s_map[s];
      nd = s_map[d];
      if (ns < 0 || nd < 0) { ns = -1; nd = -1; }
    }
    so[e] = ns;
    dq[e] = nd;
  }
}

// ---------------- pool gather + readout: grid (BATCH, 8) --------------------
// Block owns 32 cols x all rows: xnext scatter + per-column max/mean readout.
__global__ __launch_bounds__(256)
void pool_gather_kernel(const float* __restrict__ y,
                        const int* __restrict__ g_map, const float* __restrict__ g_tanh,
                        const float* __restrict__ stats, const float* __restrict__ gamma,
                        const float* __restrict__ beta,
                        float* __restrict__ xnext, float* __restrict__ total,
                        int n, int k, int accumulate) {
  const int b = blockIdx.x, chunk = blockIdx.y;
  const int tid = threadIdx.x;
  const int lane = tid & 7;          // 8 float4 lanes = 32 cols
  const int grp = tid >> 3;          // 32 row-groups
  const int cb = chunk * 8;          // float4 column base
  const float4 mean = ((const float4*)stats)[cb + lane];
  const float4 inv = ((const float4*)(stats + 256))[cb + lane];
  const float4 ga = ((const float4*)gamma)[cb + lane];
  const float4 be = ((const float4*)beta)[cb + lane];
  const float4* y4 = (const float4*)y + (size_t)b * n * 64;
  float4* xn4 = (float4*)xnext + (size_t)b * k * 64;
  float4 mx = make_float4(-INFINITY, -INFINITY, -INFINITY, -INFINITY);
  float4 sm = make_float4(0.f, 0.f, 0.f, 0.f);
  for (int i = grp; i < n; i += 32) {
    int r = g_map[b * n + i];
    if (r < 0) continue;
    float tv = g_tanh[b * n + i];
    float4 v = y4[(size_t)i * 64 + cb + lane];
    float4 o;
    o.x = gelu_f((v.x - mean.x) * inv.x * ga.x + be.x) * tv;
    o.y = gelu_f((v.y - mean.y) * inv.y * ga.y + be.y) * tv;
    o.z = gelu_f((v.z - mean.z) * inv.z * ga.z + be.z) * tv;
    o.w = gelu_f((v.w - mean.w) * inv.w * ga.w + be.w) * tv;
    xn4[(size_t)r * 64 + cb + lane] = o;
    mx.x = fmaxf(mx.x, o.x); mx.y = fmaxf(mx.y, o.y);
    mx.z = fmaxf(mx.z, o.z); mx.w = fmaxf(mx.w, o.w);
    sm.x += o.x; sm.y += o.y; sm.z += o.z; sm.w += o.w;
  }
  // reduce over the 32 row-groups (stride multiples of 8 preserve lane)
  __shared__ float4 s_mx[256];
  __shared__ float4 s_sm[256];
  s_mx[tid] = mx; s_sm[tid] = sm;
  __syncthreads();
  for (int off = 128; off >= 8; off >>= 1) {
    if (tid < off) {
      float4 a = s_mx[tid], bb = s_mx[tid + off];
      a.x = fmaxf(a.x, bb.x); a.y = fmaxf(a.y, bb.y);
      a.z = fmaxf(a.z, bb.z); a.w = fmaxf(a.w, bb.w);
      s_mx[tid] = a;
      float4 c = s_sm[tid], d = s_sm[tid + off];
      c.x += d.x; c.y += d.y; c.z += d.z; c.w += d.w;
      s_sm[tid] = c;
    }
    __syncthreads();
  }
  if (tid < 8) {
    float4 fmx = s_mx[tid], fsm = s_sm[tid];
    float* tb = total + b * 512;
    const int cbase = chunk * 32 + tid * 4;
    const float invk = 1.f / (float)k;
    float mvals[4] = {fmx.x, fmx.y, fmx.z, fmx.w};
    float svals[4] = {fsm.x, fsm.y, fsm.z, fsm.w};
#pragma unroll
    for (int j = 0; j < 4; ++j) {
      float av = svals[j] * invk;
      if (accumulate) { tb[cbase + j] += mvals[j]; tb[256 + cbase + j] += av; }
      else            { tb[cbase + j] = mvals[j];  tb[256 + cbase + j] = av; }
    }
  }
}

// ---------------- out = total @ Wlin + blin ---------------------------------
__global__ __launch_bounds__(256)
void final_linear_kernel(const float* __restrict__ total, const float* __restrict__ Wlin,
                         const float* __restrict__ blin, float* __restrict__ out) {
  const int b = blockIdx.x, o = threadIdx.x;
  __shared__ float tl[512];
  tl[o] = total[b * 512 + o];
  tl[256 + o] = total[b * 512 + 256 + o];
  __syncthreads();
  float acc = blin[o];
  for (int cc = 0; cc < 512; ++cc) acc += tl[cc] * Wlin[cc * 256 + o];
  out[b * 256 + o] = acc;
}

// ---------------- per-layer driver ------------------------------------------
template<int NN, int FF>
static void run_layer(const float* xin,
                      const int* src_in, int sstr, const int* dst_in, int dstr,
                      int* src_out, int* dst_out,
                      const float* const* P,  // W1,b1,W2,b2,gamma,beta,pw
                      int* g_rs, int* g_ids, int* g_map, float* g_tanh,
                      __hip_bfloat16* Ahi, __hip_bfloat16* Alo,
                      __hip_bfloat16* Thi, __hip_bfloat16* Tlo,
                      __hip_bfloat16* W1hi, __hip_bfloat16* W1lo,
                      __hip_bfloat16* W2hi, __hip_bfloat16* W2lo,
                      float* y, float* scores, float* stats,
                      float* P1, float* P2,
                      float* xnext, float* total, int accumulate,
                      hipStream_t stream) {
  constexpr int M = BATCH * NN;
  constexpr int ZS = (NN == 256) ? 2 : 1;   // row-split for occupancy on layer 1
  csr_build_kernel<NN><<<BATCH, 256, 0, stream>>>(src_in, sstr, dst_in, dstr, g_rs, g_ids);
  gin_gather_kernel<NN, FF, ZS><<<dim3(BATCH, FF / 32, ZS), 256, 0, stream>>>(
      xin, g_rs, g_ids, Ahi, Alo);
  wsplit_kernel<FF><<<FF, 256, 0, stream>>>(P[0], W1hi, W1lo);
  wsplit_kernel<256><<<256, 256, 0, stream>>>(P[2], W2hi, W2lo);
  mfma_gemm_kernel<FF, 1><<<dim3(M / 128, 2), 256, 0, stream>>>(
      Ahi, Alo, W1hi, W1lo, P[1], nullptr, Thi, Tlo, nullptr, nullptr);
  mfma_gemm_kernel<256, 0><<<dim3(M / 128, 2), 256, 0, stream>>>(
      Thi, Tlo, W2hi, W2lo, P[3], y, nullptr, nullptr, P1, P2);
  bn_finalize_kernel<<<256, 256, 0, stream>>>(P1, P2, M, M / 128, P[6], stats);
  score_kernel<<<M / SC_ROWS, 256, 0, stream>>>(y, stats, P[4], P[5], P[6], scores);
  topk_kernel<<<BATCH, 256, 0, stream>>>(scores, src_in, sstr, dst_in, dstr,
                                         src_out, dst_out, g_map, g_tanh, NN, NN / 2);
  pool_gather_kernel<<<dim3(BATCH, 8), 256, 0, stream>>>(
      y, g_map, g_tanh, stats, P[4], P[5], xnext, total, NN, NN / 2, accumulate);
}

extern "C" void kernel_launch(void* const* d_in, const int* in_sizes, int n_in,
                              void* d_out, int out_size, void* d_ws, size_t ws_size,
                              hipStream_t stream) {
  (void)in_sizes; (void)n_in; (void)out_size; (void)ws_size;
  const float* x0 = (const float*)d_in[0];
  const int* ei = (const int*)d_in[1];
  const float* Wlin = (const float*)d_in[30];
  const float* blin = (const float*)d_in[31];
  const float* Lp[4][7];
  for (int l = 0; l < 4; ++l)
    for (int j = 0; j < 7; ++j)
      Lp[l][j] = (const float*)d_in[2 + l * 7 + j];

  char* ws = (char*)d_ws;
  size_t off = 0;
  auto alloc = [&](size_t bytes) -> void* {
    void* p = ws + off;
    off += (bytes + 255) & ~(size_t)255;
    return p;
  };
  float* xA = (float*)alloc((size_t)BATCH * 128 * 256 * 4);        // pooled x
  float* y = (float*)alloc((size_t)BATCH * 256 * 256 * 4);         // gemm2 out
  __hip_bfloat16* Ahi = (__hip_bfloat16*)alloc((size_t)8388608 * 2);
  __hip_bfloat16* Alo = (__hip_bfloat16*)alloc((size_t)8388608 * 2);
  __hip_bfloat16* Thi = (__hip_bfloat16*)alloc((size_t)BATCH * 256 * 256 * 2);
  __hip_bfloat16* Tlo = (__hip_bfloat16*)alloc((size_t)BATCH * 256 * 256 * 2);
  __hip_bfloat16* W1hi = (__hip_bfloat16*)alloc((size_t)256 * 256 * 2);
  __hip_bfloat16* W1lo = (__hip_bfloat16*)alloc((size_t)256 * 256 * 2);
  __hip_bfloat16* W2hi = (__hip_bfloat16*)alloc((size_t)256 * 256 * 2);
  __hip_bfloat16* W2lo = (__hip_bfloat16*)alloc((size_t)256 * 256 * 2);
  float* scores = (float*)alloc((size_t)BATCH * 256 * 4);
  float* stats = (float*)alloc(4096);
  float* P1 = (float*)alloc((size_t)512 * 256 * 4);   // max M/128 = 512 row-blocks
  float* P2 = (float*)alloc((size_t)512 * 256 * 4);
  int* es0 = (int*)alloc((size_t)BATCH * NEDGE * 4);
  int* ed0 = (int*)alloc((size_t)BATCH * NEDGE * 4);
  int* es1 = (int*)alloc((size_t)BATCH * NEDGE * 4);
  int* ed1 = (int*)alloc((size_t)BATCH * NEDGE * 4);
  int* g_rs = (int*)alloc((size_t)BATCH * 257 * 4);
  int* g_ids = (int*)alloc((size_t)BATCH * NEDGE * 4);
  int* g_map = (int*)alloc((size_t)BATCH * 256 * 4);
  float* g_tanh = (float*)alloc((size_t)BATCH * 256 * 4);
  float* total = (float*)alloc((size_t)BATCH * 512 * 4);

  // layer 1: n=256, F=128; edges straight from edge_index (B,2,E)
  run_layer<256, 128>(x0, ei, 2 * NEDGE, ei + NEDGE, 2 * NEDGE, es0, ed0,
                      Lp[0], g_rs, g_ids, g_map, g_tanh,
                      Ahi, Alo, Thi, Tlo, W1hi, W1lo, W2hi, W2lo,
                      y, scores, stats, P1, P2, xA, total, 0, stream);
  // layer 2: n=128, F=256
  run_layer<128, 256>(xA, es0, NEDGE, ed0, NEDGE, es1, ed1,
                      Lp[1], g_rs, g_ids, g_map, g_tanh,
                      Ahi, Alo, Thi, Tlo, W1hi, W1lo, W2hi, W2lo,
                      y, scores, stats, P1, P2, xA, total, 1, stream);
  // layer 3: n=64, F=256
  run_layer<64, 256>(xA, es1, NEDGE, ed1, NEDGE, es0, ed0,
                     Lp[2], g_rs, g_ids, g_map, g_tanh,
                     Ahi, Alo, Thi, Tlo, W1hi, W1lo, W2hi, W2lo,
                     y, scores, stats, P1, P2, xA, total, 1, stream);
  // layer 4: n=32, F=256
  run_layer<32, 256>(xA, es0, NEDGE, ed0, NEDGE, es1, ed1,
                     Lp[3], g_rs, g_ids, g_map, g_tanh,
                     Ahi, Alo, Thi, Tlo, W1hi, W1lo, W2hi, W2lo,
                     y, scores, stats, P1, P2, xA, total, 1, stream);

  final_linear_kernel<<<BATCH, 256, 0, stream>>>(total, Wlin, blin, (float*)d_out);
}

// Round 13
// 688.000 us; speedup vs baseline: 1.6515x; 1.1441x over previous
//
#include <hip/hip_runtime.h>
#include <hip/hip_bf16.h>
#include <math.h>

#define BATCH 256
#define NEDGE 4096
#define HDIM 256

typedef __attribute__((ext_vector_type(8))) short short8v;   // 8 bf16 = 4 VGPR
typedef __attribute__((ext_vector_type(4))) float float4v;

__device__ __forceinline__ float gelu_f(float x) {
  // jax.nn.gelu approximate=True: 0.5x(1+tanh(sqrt(2/pi)(x+0.044715x^3)))
  float x3 = x * x * x;
  float t = tanhf(0.7978845608028654f * (x + 0.044715f * x3));
  return 0.5f * x * (1.0f + t);
}

__device__ __forceinline__ void split_bf16(float v, __hip_bfloat16& hi, __hip_bfloat16& lo) {
  hi = __float2bfloat16(v);
  lo = __float2bfloat16(v - __bfloat162float(hi));
}

// ---------------- CSR build: once per batch ---------------------------------
template<int NN>
__global__ __launch_bounds__(256)
void csr_build_kernel(const int* __restrict__ src_base, int src_stride,
                      const int* __restrict__ dst_base, int dst_stride,
                      int* __restrict__ g_rs,    // [BATCH][NN+1]
                      int* __restrict__ g_ids) { // [BATCH][NEDGE] (valid prefix)
  __shared__ int s_cnt[NN];          // counts, then fill cursor
  __shared__ int s_rs[NN + 1];       // CSR row starts
  __shared__ int s_csr[NEDGE];       // src ids grouped by dst
  const int b = blockIdx.x;
  const int tid = threadIdx.x;
  const int* se = src_base + (size_t)b * src_stride;
  const int* de = dst_base + (size_t)b * dst_stride;
  if (tid < NN) s_cnt[tid] = 0;
  __syncthreads();
  for (int e = tid; e < NEDGE; e += 256) {
    int s = se[e];
    if (s >= 0) atomicAdd(&s_cnt[de[e]], 1);
  }
  __syncthreads();
  if (tid < NN) s_rs[tid] = s_cnt[tid];
  __syncthreads();
  for (int off = 1; off < NN; off <<= 1) {
    int add = 0;
    if (tid < NN && tid >= off) add = s_rs[tid - off];
    __syncthreads();
    if (tid < NN) s_rs[tid] += add;
    __syncthreads();
  }
  int incl = (tid < NN) ? s_rs[tid] : 0;
  __syncthreads();
  if (tid < NN) s_rs[tid + 1] = incl;
  if (tid == 0) s_rs[0] = 0;
  if (tid < NN) s_cnt[tid] = 0;
  __syncthreads();
  for (int e = tid; e < NEDGE; e += 256) {
    int s = se[e];
    if (s >= 0) {
      int d = de[e];
      int p = s_rs[d] + atomicAdd(&s_cnt[d], 1);
      s_csr[p] = s;
    }
  }
  __syncthreads();
  const int total = s_rs[NN];
  for (int i = tid; i <= NN; i += 256) g_rs[b * (NN + 1) + i] = s_rs[i];
  for (int i = tid; i < total; i += 256) g_ids[b * NEDGE + i] = s_csr[i];
}

// ---------------- GIN gather: h = x + sum(x[src]) per dst, split-bf16 out ---
// Grid (BATCH, FF/32, ZS). ZS splits rows for occupancy on the big layer.
template<int NN, int FF, int ZS>
__global__ __launch_bounds__(256)
void gin_gather_kernel(const float* __restrict__ x,
                       const int* __restrict__ g_rs, const int* __restrict__ g_ids,
                       __hip_bfloat16* __restrict__ Hhi,
                       __hip_bfloat16* __restrict__ Hlo) {
  constexpr int LPE = 8;             // 8 lanes x float4 = 32 cols/block
  constexpr int GRP = 256 / LPE;     // 32 rows accumulated in parallel
  constexpr int F4 = FF / 4;
  __shared__ int s_rs[NN + 1];
  __shared__ int s_ids[NEDGE];
  const int b = blockIdx.x;
  const int chunk = blockIdx.y;
  const int tid = threadIdx.x;
  for (int i = tid; i <= NN; i += 256) s_rs[i] = g_rs[b * (NN + 1) + i];
  __syncthreads();
  const int total = s_rs[NN];
  for (int i = tid; i < total; i += 256) s_ids[i] = g_ids[b * NEDGE + i];
  __syncthreads();
  const int lane = tid & (LPE - 1);
  const int grp = tid / LPE;
  const int cb = chunk * LPE;        // float4 column base
  const int r0 = blockIdx.z * (NN / ZS);
  const int r1 = r0 + NN / ZS;
  const float4* x4 = (const float4*)x + (size_t)b * NN * F4;
  for (int d = r0 + grp; d < r1; d += GRP) {
    int j0 = s_rs[d], j1 = s_rs[d + 1];
    float4 acc = x4[(size_t)d * F4 + cb + lane];
    for (int j = j0; j < j1; ++j) {
      int s = s_ids[j];
      float4 xv = x4[(size_t)s * F4 + cb + lane];
      acc.x += xv.x; acc.y += xv.y; acc.z += xv.z; acc.w += xv.w;
    }
    float av[4] = {acc.x, acc.y, acc.z, acc.w};
    union { __hip_bfloat16 h[4]; uint2 u; } hv, lv;   // aligned views
#pragma unroll
    for (int j = 0; j < 4; ++j) split_bf16(av[j], hv.h[j], lv.h[j]);
    size_t eo = ((size_t)b * NN + d) * FF + (cb + lane) * 4;
    *(uint2*)&Hhi[eo] = hv.u;
    *(uint2*)&Hlo[eo] = lv.u;
  }
}

// ---------------- weight transpose + split: W[K][256] -> Wt{hi,lo}[256][K] --
template<int K>
__global__ __launch_bounds__(256)
void wsplit_kernel(const float* __restrict__ W,
                   __hip_bfloat16* __restrict__ Whi, __hip_bfloat16* __restrict__ Wlo) {
  int idx = blockIdx.x * 256 + threadIdx.x;   // over 256*K outputs
  int c = idx / K, k = idx % K;               // K pow2, compile-time
  float w = W[(size_t)k * 256 + c];
  __hip_bfloat16 hi, lo;
  split_bf16(w, hi, lo);
  Whi[idx] = hi;   // idx == c*K + k
  Wlo[idx] = lo;
}

// ---------------- fused MLP: Y = (gelu(A @ W1 + b1)) @ W2 + b2 --------------
// Split-bf16 3-product MFMA, T held in LDS (no HBM round-trip). Block = 64
// output rows x 256 cols, 4 waves (wave w owns cols w*64, 4x4 frags of
// 16x16x32). Fused BN column partials over the block's 64 rows.
template<int K1>
__global__ __launch_bounds__(256)
void fused_mlp_kernel(const __hip_bfloat16* __restrict__ Ahi,
                      const __hip_bfloat16* __restrict__ Alo,
                      const __hip_bfloat16* __restrict__ B1hi,  // [256][K1] = W1^T
                      const __hip_bfloat16* __restrict__ B1lo,
                      const float* __restrict__ b1,
                      const __hip_bfloat16* __restrict__ B2hi,  // [256][256] = W2^T
                      const __hip_bfloat16* __restrict__ B2lo,
                      const float* __restrict__ b2,
                      float* __restrict__ y,
                      float* __restrict__ P1,   // [M/64][256] col partial sums
                      float* __restrict__ P2) { // [M/64][256] col partial sq-sums
  constexpr int TSTR = 264;  // padded T row stride: 528B rows = 16B-aligned,
                             // bank shift 4 -> (lr+lg)&7 spread = b128 baseline
  __shared__ __hip_bfloat16 Ths[64 * TSTR];
  __shared__ __hip_bfloat16 Tls[64 * TSTR];
  __shared__ float bnr1[256][4];
  __shared__ float bnr2[256][4];
  const int tid = threadIdx.x;
  const int w = tid >> 6, lane = tid & 63;
  const int lr = lane & 15, lg = lane >> 4;
  const int rowBase = blockIdx.x * 64;
  const int colW = w * 64;           // wave's 64-col slice (both phases)
  float4v acc[4][4];

  // ---- phase 1: T = gelu(A @ W1 + b1), split-bf16 -> LDS
#pragma unroll
  for (int m = 0; m < 4; ++m)
#pragma unroll
    for (int n = 0; n < 4; ++n) acc[m][n] = (float4v){0.f, 0.f, 0.f, 0.f};
#pragma unroll 2
  for (int k0 = 0; k0 < K1; k0 += 32) {
    short8v ah[4], al[4], bh[4], bl[4];
#pragma unroll
    for (int m = 0; m < 4; ++m) {
      size_t off = (size_t)(rowBase + m * 16 + lr) * K1 + k0 + lg * 8;
      ah[m] = *(const short8v*)(Ahi + off);
      al[m] = *(const short8v*)(Alo + off);
    }
#pragma unroll
    for (int n = 0; n < 4; ++n) {
      size_t off = (size_t)(colW + n * 16 + lr) * K1 + k0 + lg * 8;
      bh[n] = *(const short8v*)(B1hi + off);
      bl[n] = *(const short8v*)(B1lo + off);
    }
#pragma unroll
    for (int m = 0; m < 4; ++m)
#pragma unroll
      for (int n = 0; n < 4; ++n) {
        acc[m][n] = __builtin_amdgcn_mfma_f32_16x16x32_bf16(ah[m], bh[n], acc[m][n], 0, 0, 0);
        acc[m][n] = __builtin_amdgcn_mfma_f32_16x16x32_bf16(al[m], bh[n], acc[m][n], 0, 0, 0);
        acc[m][n] = __builtin_amdgcn_mfma_f32_16x16x32_bf16(ah[m], bl[n], acc[m][n], 0, 0, 0);
      }
  }
  // epilogue 1: C/D map (col = lane&15, row = (lane>>4)*4 + i) -> LDS
#pragma unroll
  for (int n = 0; n < 4; ++n) {
    const int col = colW + n * 16 + lr;
    const float bv = b1[col];
#pragma unroll
    for (int m = 0; m < 4; ++m) {
      const int row = m * 16 + lg * 4;
#pragma unroll
      for (int i = 0; i < 4; ++i) {
        float o = gelu_f(acc[m][n][i] + bv);
        __hip_bfloat16 hi, lo;
        split_bf16(o, hi, lo);
        Ths[(row + i) * TSTR + col] = hi;
        Tls[(row + i) * TSTR + col] = lo;
      }
    }
  }
  __syncthreads();

  // ---- phase 2: Y = T @ W2 + b2 (A-fragments from LDS)
#pragma unroll
  for (int m = 0; m < 4; ++m)
#pragma unroll
    for (int n = 0; n < 4; ++n) acc[m][n] = (float4v){0.f, 0.f, 0.f, 0.f};
#pragma unroll 2
  for (int k0 = 0; k0 < 256; k0 += 32) {
    short8v ah[4], al[4], bh[4], bl[4];
#pragma unroll
    for (int m = 0; m < 4; ++m) {
      const int loff = (m * 16 + lr) * TSTR + k0 + lg * 8;
      ah[m] = *(const short8v*)(Ths + loff);
      al[m] = *(const short8v*)(Tls + loff);
    }
#pragma unroll
    for (int n = 0; n < 4; ++n) {
      size_t off = (size_t)(colW + n * 16 + lr) * 256 + k0 + lg * 8;
      bh[n] = *(const short8v*)(B2hi + off);
      bl[n] = *(const short8v*)(B2lo + off);
    }
#pragma unroll
    for (int m = 0; m < 4; ++m)
#pragma unroll
      for (int n = 0; n < 4; ++n) {
        acc[m][n] = __builtin_amdgcn_mfma_f32_16x16x32_bf16(ah[m], bh[n], acc[m][n], 0, 0, 0);
        acc[m][n] = __builtin_amdgcn_mfma_f32_16x16x32_bf16(al[m], bh[n], acc[m][n], 0, 0, 0);
        acc[m][n] = __builtin_amdgcn_mfma_f32_16x16x32_bf16(ah[m], bl[n], acc[m][n], 0, 0, 0);
      }
  }
  // epilogue 2: y write (full-line fp32) + fused BN column partials
  float s1[4] = {0.f, 0.f, 0.f, 0.f};
  float s2[4] = {0.f, 0.f, 0.f, 0.f};
#pragma unroll
  for (int n = 0; n < 4; ++n) {
    const int col = colW + n * 16 + lr;
    const float bv = b2[col];
#pragma unroll
    for (int m = 0; m < 4; ++m) {
      const int row0 = rowBase + m * 16 + lg * 4;
#pragma unroll
      for (int i = 0; i < 4; ++i) {
        float o = acc[m][n][i] + bv;
        y[(size_t)(row0 + i) * 256 + col] = o;
        s1[n] += o;
        s2[n] += o * o;
      }
    }
  }
#pragma unroll
  for (int n = 0; n < 4; ++n) {
    const int col = colW + n * 16 + lr;
    bnr1[col][lg] = s1[n];
    bnr2[col][lg] = s2[n];
  }
  __syncthreads();
  if (tid < 256) {
    float a = 0.f, b2s = 0.f;
#pragma unroll
    for (int j = 0; j < 4; ++j) { a += bnr1[tid][j]; b2s += bnr2[tid][j]; }
    size_t po = (size_t)blockIdx.x * 256 + tid;
    P1[po] = a;
    P2[po] = b2s;
  }
}

// ---------------- BN finalize: one block per column -------------------------
// stats layout: [0..255]=mean, [256..511]=rsqrt(var+eps), [512]=1/||pw||
__global__ __launch_bounds__(256)
void bn_finalize_kernel(const float* __restrict__ P1, const float* __restrict__ P2,
                        int M, int nblk, const float* __restrict__ pw,
                        float* __restrict__ stats) {
  const int c = blockIdx.x;
  const int tid = threadIdx.x;
  __shared__ double r1[256], r2[256];
  double s = 0.0, s2 = 0.0;
  for (int i = tid; i < nblk; i += 256) {
    s += (double)P1[i * 256 + c];
    s2 += (double)P2[i * 256 + c];
  }
  r1[tid] = s; r2[tid] = s2;
  __syncthreads();
  for (int off = 128; off; off >>= 1) {
    if (tid < off) { r1[tid] += r1[tid + off]; r2[tid] += r2[tid + off]; }
    __syncthreads();
  }
  if (tid == 0) {
    double mean = r1[0] / (double)M;
    double var = r2[0] / (double)M - mean * mean;
    stats[c] = (float)mean;
    stats[256 + c] = (float)(1.0 / sqrt(var + 1e-5));
  }
  if (c == 0) {   // block 0 additionally reduces ||pw||^2
    __syncthreads();
    float w = pw[tid];
    r1[tid] = (double)w * (double)w;
    __syncthreads();
    for (int off = 128; off; off >>= 1) {
      if (tid < off) r1[tid] += r1[tid + off];
      __syncthreads();
    }
    if (tid == 0) stats[512] = (float)(1.0 / sqrt(r1[0]));
  }
}

// ---------------- score[row] = dot(gelu(bn(y[row])), pw) / ||pw|| -----------
#define SC_ROWS 16
__global__ __launch_bounds__(256)
void score_kernel(const float* __restrict__ y, const float* __restrict__ stats,
                  const float* __restrict__ gamma, const float* __restrict__ beta,
                  const float* __restrict__ pw, float* __restrict__ scores) {
  const int tid = threadIdx.x;
  const int lane = tid & 63, wid = tid >> 6;
  const float4 mean = ((const float4*)stats)[lane];
  const float4 inv = ((const float4*)(stats + 256))[lane];
  const float4 ga = ((const float4*)gamma)[lane];
  const float4 be = ((const float4*)beta)[lane];
  const float4 w = ((const float4*)pw)[lane];
  const float invn = stats[512];
#pragma unroll
  for (int i = 0; i < SC_ROWS / 4; ++i) {
    const int row = blockIdx.x * SC_ROWS + wid + 4 * i;
    float4 v = ((const float4*)y)[(size_t)row * 64 + lane];
    float p = gelu_f((v.x - mean.x) * inv.x * ga.x + be.x) * w.x
            + gelu_f((v.y - mean.y) * inv.y * ga.y + be.y) * w.y
            + gelu_f((v.z - mean.z) * inv.z * ga.z + be.z) * w.z
            + gelu_f((v.w - mean.w) * inv.w * ga.w + be.w) * w.w;
    p *= invn;
#pragma unroll
    for (int off = 32; off; off >>= 1) p += __shfl_xor(p, off, 64);
    if (lane == 0) scores[row] = p;
  }
}

// ---------------- top-k select + edge remap (block per batch) ---------------
__global__ __launch_bounds__(256)
void topk_kernel(const float* __restrict__ scores,
                 const int* __restrict__ src_in, int src_stride,
                 const int* __restrict__ dst_in, int dst_stride,
                 int* __restrict__ src_out, int* __restrict__ dst_out,
                 int* __restrict__ g_map, float* __restrict__ g_tanh,
                 int n, int k) {
  const int b = blockIdx.x;
  const int tid = threadIdx.x;
  __shared__ float s_sc[256];
  __shared__ int s_map[256];
  if (tid < n) s_sc[tid] = scores[b * n + tid];
  __syncthreads();
  if (tid < n) {
    // rank = #nodes strictly ahead (ties: lower index first, matches lax.top_k)
    float si = s_sc[tid];
    int r = 0;
    for (int j = 0; j < n; ++j) {
      float sj = s_sc[j];
      r += (sj > si) || (sj == si && j < tid);
    }
    int m = (r < k) ? r : -1;
    s_map[tid] = m;
    g_map[b * n + tid] = m;
    g_tanh[b * n + tid] = tanhf(si);
  }
  __syncthreads();
  const int* se = src_in + (size_t)b * src_stride;
  const int* de = dst_in + (size_t)b * dst_stride;
  int* so = src_out + (size_t)b * NEDGE;
  int* dq = dst_out + (size_t)b * NEDGE;
  for (int e = tid; e < NEDGE; e += 256) {
    int s = se[e], d = de[e];
    int ns = -1, nd = -1;
    if (s >= 0 && d >= 0) {
      ns = s_map[s];
      nd = s_map[d];
      if (ns < 0 || nd < 0) { ns = -1; nd = -1; }
    }
    so[e] = ns;
    dq[e] = nd;
  }
}

// ---------------- pool gather + readout: grid (BATCH, 8) --------------------
// Block owns 32 cols x all rows: xnext scatter + per-column max/mean readout.
__global__ __launch_bounds__(256)
void pool_gather_kernel(const float* __restrict__ y,
                        const int* __restrict__ g_map, const float* __restrict__ g_tanh,
                        const float* __restrict__ stats, const float* __restrict__ gamma,
                        const float* __restrict__ beta,
                        float* __restrict__ xnext, float* __restrict__ total,
                        int n, int k, int accumulate) {
  const int b = blockIdx.x, chunk = blockIdx.y;
  const int tid = threadIdx.x;
  const int lane = tid & 7;          // 8 float4 lanes = 32 cols
  const int grp = tid >> 3;          // 32 row-groups
  const int cb = chunk * 8;          // float4 column base
  const float4 mean = ((const float4*)stats)[cb + lane];
  const float4 inv = ((const float4*)(stats + 256))[cb + lane];
  const float4 ga = ((const float4*)gamma)[cb + lane];
  const float4 be = ((const float4*)beta)[cb + lane];
  const float4* y4 = (const float4*)y + (size_t)b * n * 64;
  float4* xn4 = (float4*)xnext + (size_t)b * k * 64;
  float4 mx = make_float4(-INFINITY, -INFINITY, -INFINITY, -INFINITY);
  float4 sm = make_float4(0.f, 0.f, 0.f, 0.f);
  for (int i = grp; i < n; i += 32) {
    int r = g_map[b * n + i];
    if (r < 0) continue;
    float tv = g_tanh[b * n + i];
    float4 v = y4[(size_t)i * 64 + cb + lane];
    float4 o;
    o.x = gelu_f((v.x - mean.x) * inv.x * ga.x + be.x) * tv;
    o.y = gelu_f((v.y - mean.y) * inv.y * ga.y + be.y) * tv;
    o.z = gelu_f((v.z - mean.z) * inv.z * ga.z + be.z) * tv;
    o.w = gelu_f((v.w - mean.w) * inv.w * ga.w + be.w) * tv;
    xn4[(size_t)r * 64 + cb + lane] = o;
    mx.x = fmaxf(mx.x, o.x); mx.y = fmaxf(mx.y, o.y);
    mx.z = fmaxf(mx.z, o.z); mx.w = fmaxf(mx.w, o.w);
    sm.x += o.x; sm.y += o.y; sm.z += o.z; sm.w += o.w;
  }
  // reduce over the 32 row-groups (stride multiples of 8 preserve lane)
  __shared__ float4 s_mx[256];
  __shared__ float4 s_sm[256];
  s_mx[tid] = mx; s_sm[tid] = sm;
  __syncthreads();
  for (int off = 128; off >= 8; off >>= 1) {
    if (tid < off) {
      float4 a = s_mx[tid], bb = s_mx[tid + off];
      a.x = fmaxf(a.x, bb.x); a.y = fmaxf(a.y, bb.y);
      a.z = fmaxf(a.z, bb.z); a.w = fmaxf(a.w, bb.w);
      s_mx[tid] = a;
      float4 c = s_sm[tid], d = s_sm[tid + off];
      c.x += d.x; c.y += d.y; c.z += d.z; c.w += d.w;
      s_sm[tid] = c;
    }
    __syncthreads();
  }
  if (tid < 8) {
    float4 fmx = s_mx[tid], fsm = s_sm[tid];
    float* tb = total + b * 512;
    const int cbase = chunk * 32 + tid * 4;
    const float invk = 1.f / (float)k;
    float mvals[4] = {fmx.x, fmx.y, fmx.z, fmx.w};
    float svals[4] = {fsm.x, fsm.y, fsm.z, fsm.w};
#pragma unroll
    for (int j = 0; j < 4; ++j) {
      float av = svals[j] * invk;
      if (accumulate) { tb[cbase + j] += mvals[j]; tb[256 + cbase + j] += av; }
      else            { tb[cbase + j] = mvals[j];  tb[256 + cbase + j] = av; }
    }
  }
}

// ---------------- out = total @ Wlin + blin ---------------------------------
__global__ __launch_bounds__(256)
void final_linear_kernel(const float* __restrict__ total, const float* __restrict__ Wlin,
                         const float* __restrict__ blin, float* __restrict__ out) {
  const int b = blockIdx.x, o = threadIdx.x;
  __shared__ float tl[512];
  tl[o] = total[b * 512 + o];
  tl[256 + o] = total[b * 512 + 256 + o];
  __syncthreads();
  float acc = blin[o];
  for (int cc = 0; cc < 512; ++cc) acc += tl[cc] * Wlin[cc * 256 + o];
  out[b * 256 + o] = acc;
}

// ---------------- per-layer driver ------------------------------------------
template<int NN, int FF>
static void run_layer(const float* xin,
                      const int* src_in, int sstr, const int* dst_in, int dstr,
                      int* src_out, int* dst_out,
                      const float* const* P,  // W1,b1,W2,b2,gamma,beta,pw
                      int* g_rs, int* g_ids, int* g_map, float* g_tanh,
                      __hip_bfloat16* Ahi, __hip_bfloat16* Alo,
                      __hip_bfloat16* W1hi, __hip_bfloat16* W1lo,
                      __hip_bfloat16* W2hi, __hip_bfloat16* W2lo,
                      float* y, float* scores, float* stats,
                      float* P1, float* P2,
                      float* xnext, float* total, int accumulate,
                      hipStream_t stream) {
  constexpr int M = BATCH * NN;
  constexpr int ZS = (NN == 256) ? 2 : 1;   // row-split for occupancy on layer 1
  csr_build_kernel<NN><<<BATCH, 256, 0, stream>>>(src_in, sstr, dst_in, dstr, g_rs, g_ids);
  gin_gather_kernel<NN, FF, ZS><<<dim3(BATCH, FF / 32, ZS), 256, 0, stream>>>(
      xin, g_rs, g_ids, Ahi, Alo);
  wsplit_kernel<FF><<<FF, 256, 0, stream>>>(P[0], W1hi, W1lo);
  wsplit_kernel<256><<<256, 256, 0, stream>>>(P[2], W2hi, W2lo);
  fused_mlp_kernel<FF><<<M / 64, 256, 0, stream>>>(
      Ahi, Alo, W1hi, W1lo, P[1], W2hi, W2lo, P[3], y, P1, P2);
  bn_finalize_kernel<<<256, 256, 0, stream>>>(P1, P2, M, M / 64, P[6], stats);
  score_kernel<<<M / SC_ROWS, 256, 0, stream>>>(y, stats, P[4], P[5], P[6], scores);
  topk_kernel<<<BATCH, 256, 0, stream>>>(scores, src_in, sstr, dst_in, dstr,
                                         src_out, dst_out, g_map, g_tanh, NN, NN / 2);
  pool_gather_kernel<<<dim3(BATCH, 8), 256, 0, stream>>>(
      y, g_map, g_tanh, stats, P[4], P[5], xnext, total, NN, NN / 2, accumulate);
}

extern "C" void kernel_launch(void* const* d_in, const int* in_sizes, int n_in,
                              void* d_out, int out_size, void* d_ws, size_t ws_size,
                              hipStream_t stream) {
  (void)in_sizes; (void)n_in; (void)out_size; (void)ws_size;
  const float* x0 = (const float*)d_in[0];
  const int* ei = (const int*)d_in[1];
  const float* Wlin = (const float*)d_in[30];
  const float* blin = (const float*)d_in[31];
  const float* Lp[4][7];
  for (int l = 0; l < 4; ++l)
    for (int j = 0; j < 7; ++j)
      Lp[l][j] = (const float*)d_in[2 + l * 7 + j];

  char* ws = (char*)d_ws;
  size_t off = 0;
  auto alloc = [&](size_t bytes) -> void* {
    void* p = ws + off;
    off += (bytes + 255) & ~(size_t)255;
    return p;
  };
  float* xA = (float*)alloc((size_t)BATCH * 128 * 256 * 4);        // pooled x
  float* y = (float*)alloc((size_t)BATCH * 256 * 256 * 4);         // fused out
  __hip_bfloat16* Ahi = (__hip_bfloat16*)alloc((size_t)8388608 * 2);
  __hip_bfloat16* Alo = (__hip_bfloat16*)alloc((size_t)8388608 * 2);
  __hip_bfloat16* W1hi = (__hip_bfloat16*)alloc((size_t)256 * 256 * 2);
  __hip_bfloat16* W1lo = (__hip_bfloat16*)alloc((size_t)256 * 256 * 2);
  __hip_bfloat16* W2hi = (__hip_bfloat16*)alloc((size_t)256 * 256 * 2);
  __hip_bfloat16* W2lo = (__hip_bfloat16*)alloc((size_t)256 * 256 * 2);
  float* scores = (float*)alloc((size_t)BATCH * 256 * 4);
  float* stats = (float*)alloc(4096);
  float* P1 = (float*)alloc((size_t)1024 * 256 * 4);   // max M/64 = 1024 row-blocks
  float* P2 = (float*)alloc((size_t)1024 * 256 * 4);
  int* es0 = (int*)alloc((size_t)BATCH * NEDGE * 4);
  int* ed0 = (int*)alloc((size_t)BATCH * NEDGE * 4);
  int* es1 = (int*)alloc((size_t)BATCH * NEDGE * 4);
  int* ed1 = (int*)alloc((size_t)BATCH * NEDGE * 4);
  int* g_rs = (int*)alloc((size_t)BATCH * 257 * 4);
  int* g_ids = (int*)alloc((size_t)BATCH * NEDGE * 4);
  int* g_map = (int*)alloc((size_t)BATCH * 256 * 4);
  float* g_tanh = (float*)alloc((size_t)BATCH * 256 * 4);
  float* total = (float*)alloc((size_t)BATCH * 512 * 4);

  // layer 1: n=256, F=128; edges straight from edge_index (B,2,E)
  run_layer<256, 128>(x0, ei, 2 * NEDGE, ei + NEDGE, 2 * NEDGE, es0, ed0,
                      Lp[0], g_rs, g_ids, g_map, g_tanh,
                      Ahi, Alo, W1hi, W1lo, W2hi, W2lo,
                      y, scores, stats, P1, P2, xA, total, 0, stream);
  // layer 2: n=128, F=256
  run_layer<128, 256>(xA, es0, NEDGE, ed0, NEDGE, es1, ed1,
                      Lp[1], g_rs, g_ids, g_map, g_tanh,
                      Ahi, Alo, W1hi, W1lo, W2hi, W2lo,
                      y, scores, stats, P1, P2, xA, total, 1, stream);
  // layer 3: n=64, F=256
  run_layer<64, 256>(xA, es1, NEDGE, ed1, NEDGE, es0, ed0,
                     Lp[2], g_rs, g_ids, g_map, g_tanh,
                     Ahi, Alo, W1hi, W1lo, W2hi, W2lo,
                     y, scores, stats, P1, P2, xA, total, 1, stream);
  // layer 4: n=32, F=256
  run_layer<32, 256>(xA, es0, NEDGE, ed0, NEDGE, es1, ed1,
                     Lp[3], g_rs, g_ids, g_map, g_tanh,
                     Ahi, Alo, W1hi, W1lo, W2hi, W2lo,
                     y, scores, stats, P1, P2, xA, total, 1, stream);

  final_linear_kernel<<<BATCH, 256, 0, stream>>>(total, Wlin, blin, (float*)d_out);
}